// Round 1
// baseline (533.374 us; speedup 1.0000x reference)
//
#include <hip/hip_runtime.h>
#include <math.h>

// Problem constants (shapes fixed by the reference):
// N=10000, E=640000, D=128, H1=256, H2=256, OUT=64
#define D_DIM   128
#define H1_DIM  256
#define H2_DIM  256
#define OUT_DIM 64
#define LN_EPS  1e-5f

// ---------------------------------------------------------------------------
// K0: constants — coef = softplus(ewmc), mpb = mean(pool_b), mpb2 = mean(pool_b^2)
// ---------------------------------------------------------------------------
__global__ void k_setup(const float* __restrict__ ewmc,
                        const float* __restrict__ pb,
                        float* __restrict__ consts) {
    __shared__ float s1[128], s2[128];
    int t = threadIdx.x;
    float v = pb[t];
    s1[t] = v;
    s2[t] = v * v;
    __syncthreads();
    for (int off = 64; off; off >>= 1) {
        if (t < off) { s1[t] += s1[t + off]; s2[t] += s2[t + off]; }
        __syncthreads();
    }
    if (t == 0) {
        float xw = ewmc[0];
        float coef = (xw > 30.f) ? xw : log1pf(expf(xw));
        consts[0] = coef;
        consts[1] = s1[0] * (1.f / 128.f);   // mean(pool_b)
        consts[2] = s2[0] * (1.f / 128.f);   // mean(pool_b^2)
    }
}

// ---------------------------------------------------------------------------
// K1: y = x @ pool_w (no bias) + per-node stats:
//     sy = mean_d(y), sy2 = mean_d(y^2), syp = mean_d(y * pool_b)
// 8 rows per block of 128 threads (weight element reused 8x in registers).
// ---------------------------------------------------------------------------
__global__ __launch_bounds__(128) void k_pool(
        const float* __restrict__ x, const float* __restrict__ pw,
        const float* __restrict__ pb,
        float* __restrict__ y, float* __restrict__ sy,
        float* __restrict__ sy2, float* __restrict__ syp) {
    __shared__ float xs[8][129];
    __shared__ float ys[8][129];
    __shared__ float pbs[128];
    int tid = threadIdx.x;
    int row0 = blockIdx.x * 8;
    pbs[tid] = pb[tid];
#pragma unroll
    for (int r = 0; r < 8; ++r) xs[r][tid] = x[(row0 + r) * D_DIM + tid];
    __syncthreads();
    float acc[8];
#pragma unroll
    for (int r = 0; r < 8; ++r) acc[r] = 0.f;
    for (int k = 0; k < D_DIM; ++k) {
        float w = pw[k * D_DIM + tid];
#pragma unroll
        for (int r = 0; r < 8; ++r) acc[r] = fmaf(xs[r][k], w, acc[r]);
    }
#pragma unroll
    for (int r = 0; r < 8; ++r) {
        y[(row0 + r) * D_DIM + tid] = acc[r];
        ys[r][tid] = acc[r];
    }
    __syncthreads();
    if (tid < 24) {
        int r = tid / 3, which = tid % 3;
        float s = 0.f;
        if (which == 0)      for (int k = 0; k < D_DIM; ++k) s += ys[r][k];
        else if (which == 1) for (int k = 0; k < D_DIM; ++k) s += ys[r][k] * ys[r][k];
        else                 for (int k = 0; k < D_DIM; ++k) s += ys[r][k] * pbs[k];
        s *= (1.f / 128.f);
        if (which == 0)      sy [row0 + r] = s;
        else if (which == 1) sy2[row0 + r] = s;
        else                 syp[row0 + r] = s;
    }
}

// ---------------------------------------------------------------------------
// K2: per-edge pooled = relu(LN(s*y[src] + pb)) and segment-max into agg[dst]
// via atomicMax on int bits (valid: all values >= 0, agg zero-initialized).
// One wave per edge; each lane owns 2 of the 128 dims.
// ---------------------------------------------------------------------------
__global__ __launch_bounds__(256) void k_edge(
        const int* __restrict__ ei, const float* __restrict__ es,
        const float* __restrict__ consts,
        const float* __restrict__ y, const float* __restrict__ sy,
        const float* __restrict__ sy2, const float* __restrict__ syp,
        const float* __restrict__ pb, const float* __restrict__ g,
        const float* __restrict__ b, int* __restrict__ agg, int E) {
    const float coef = consts[0], mpb = consts[1], mpb2 = consts[2];
    const int lane = threadIdx.x & 63;
    const int waveId = (blockIdx.x * blockDim.x + threadIdx.x) >> 6;
    const int nWaves = (gridDim.x * blockDim.x) >> 6;
    const int d0 = lane * 2;
    const float2 pbv = *(const float2*)&pb[d0];
    const float2 gv  = *(const float2*)&g[d0];
    const float2 bv  = *(const float2*)&b[d0];
    for (int e = waveId; e < E; e += nWaves) {
        int src = ei[e];
        int dst = ei[E + e];
        float s = fmaf(coef, es[e], 1.0f);
        float m   = fmaf(s, sy[src], mpb);
        float et2 = s * s * sy2[src] + 2.f * s * syp[src] + mpb2;
        float v = et2 - m * m;
        float inv = rsqrtf(v + LN_EPS);
        float2 yv = *(const float2*)&y[src * D_DIM + d0];
        float t0 = fmaf(s, yv.x, pbv.x);
        float t1 = fmaf(s, yv.y, pbv.y);
        float o0 = fmaxf(fmaf((t0 - m) * inv, gv.x, bv.x), 0.f);
        float o1 = fmaxf(fmaf((t1 - m) * inv, gv.y, bv.y), 0.f);
        int base = dst * D_DIM + d0;
        atomicMax(&agg[base],     __float_as_int(o0));
        atomicMax(&agg[base + 1], __float_as_int(o1));
    }
}

// ---------------------------------------------------------------------------
// K3: fused MLP head. 8 rows per block of 256 threads, all hidden state in LDS.
// h1 = relu(LN(agg@w1+b1)); h2 = relu(LN(h1@w2+b2));
// mu = h2@mu_w+mu_b; std = exp(0.5*(h2@lv_w+lv_b)).
// ---------------------------------------------------------------------------
__global__ __launch_bounds__(256) void k_mlp(
        const float* __restrict__ agg,
        const float* __restrict__ w1, const float* __restrict__ b1,
        const float* __restrict__ g1, const float* __restrict__ bb1,
        const float* __restrict__ w2, const float* __restrict__ b2,
        const float* __restrict__ g2, const float* __restrict__ bb2,
        const float* __restrict__ muw, const float* __restrict__ mub,
        const float* __restrict__ lvw, const float* __restrict__ lvb,
        float* __restrict__ out, int N) {
    __shared__ float sIn[8][129];
    __shared__ float sH[8][257];
    __shared__ float sH2[8][257];
    __shared__ float sStat[8][2];
    const int tid = threadIdx.x;
    const int row0 = blockIdx.x * 8;

    for (int i = tid; i < 8 * D_DIM; i += 256)
        sIn[i >> 7][i & 127] = agg[row0 * D_DIM + i];
    __syncthreads();

    // ---- layer 1: h1[o] = dot(agg_row, w1[:,o]) + b1[o]
    float acc[8];
#pragma unroll
    for (int r = 0; r < 8; ++r) acc[r] = 0.f;
    for (int k = 0; k < D_DIM; ++k) {
        float w = w1[k * H1_DIM + tid];
#pragma unroll
        for (int r = 0; r < 8; ++r) acc[r] = fmaf(sIn[r][k], w, acc[r]);
    }
    {
        float bias = b1[tid];
#pragma unroll
        for (int r = 0; r < 8; ++r) { acc[r] += bias; sH[r][tid] = acc[r]; }
    }
    __syncthreads();
    if (tid < 16) {
        int r = tid >> 1, which = tid & 1;
        float s = 0.f;
        if (which == 0) for (int k = 0; k < H1_DIM; ++k) s += sH[r][k];
        else            for (int k = 0; k < H1_DIM; ++k) s += sH[r][k] * sH[r][k];
        sStat[r][which] = s * (1.f / 256.f);
    }
    __syncthreads();
    {
        float gv = g1[tid], bv = bb1[tid];
#pragma unroll
        for (int r = 0; r < 8; ++r) {
            float m = sStat[r][0];
            float v = sStat[r][1] - m * m;
            acc[r] = fmaxf(fmaf((acc[r] - m) * rsqrtf(v + LN_EPS), gv, bv), 0.f);
        }
    }
    __syncthreads();  // stats readers done before overwrite
#pragma unroll
    for (int r = 0; r < 8; ++r) sH[r][tid] = acc[r];
    __syncthreads();

    // ---- layer 2: h2[o] = dot(h1_row, w2[:,o]) + b2[o]
    float acc2[8];
#pragma unroll
    for (int r = 0; r < 8; ++r) acc2[r] = 0.f;
    for (int k = 0; k < H1_DIM; ++k) {
        float w = w2[k * H2_DIM + tid];
#pragma unroll
        for (int r = 0; r < 8; ++r) acc2[r] = fmaf(sH[r][k], w, acc2[r]);
    }
    {
        float bias = b2[tid];
#pragma unroll
        for (int r = 0; r < 8; ++r) { acc2[r] += bias; sH2[r][tid] = acc2[r]; }
    }
    __syncthreads();
    if (tid < 16) {
        int r = tid >> 1, which = tid & 1;
        float s = 0.f;
        if (which == 0) for (int k = 0; k < H2_DIM; ++k) s += sH2[r][k];
        else            for (int k = 0; k < H2_DIM; ++k) s += sH2[r][k] * sH2[r][k];
        sStat[r][which] = s * (1.f / 256.f);
    }
    __syncthreads();
    {
        float gv = g2[tid], bv = bb2[tid];
#pragma unroll
        for (int r = 0; r < 8; ++r) {
            float m = sStat[r][0];
            float v = sStat[r][1] - m * m;
            acc2[r] = fmaxf(fmaf((acc2[r] - m) * rsqrtf(v + LN_EPS), gv, bv), 0.f);
        }
    }
    __syncthreads();
#pragma unroll
    for (int r = 0; r < 8; ++r) sH2[r][tid] = acc2[r];
    __syncthreads();

    // ---- output heads: mu (cols 0..63) and std = exp(0.5*logvar)
    const int col   = tid & 63;
    const int which = (tid >> 6) & 1;   // 0 = mu, 1 = logvar
    const int rh    = tid >> 7;         // row half: rows rh*4 .. rh*4+3
    const float* W  = which ? lvw : muw;
    const float ob  = which ? lvb[col] : mub[col];
    float a[4];
#pragma unroll
    for (int rr = 0; rr < 4; ++rr) a[rr] = 0.f;
    for (int k = 0; k < H2_DIM; ++k) {
        float w = W[k * OUT_DIM + col];
#pragma unroll
        for (int rr = 0; rr < 4; ++rr) a[rr] = fmaf(sH2[rh * 4 + rr][k], w, a[rr]);
    }
#pragma unroll
    for (int rr = 0; rr < 4; ++rr) {
        int row = row0 + rh * 4 + rr;
        float val = a[rr] + ob;
        if (which == 0) out[(size_t)row * OUT_DIM + col] = val;
        else            out[(size_t)N * OUT_DIM + (size_t)row * OUT_DIM + col] = expf(0.5f * val);
    }
}

// ---------------------------------------------------------------------------
extern "C" void kernel_launch(void* const* d_in, const int* in_sizes, int n_in,
                              void* d_out, int out_size, void* d_ws, size_t ws_size,
                              hipStream_t stream) {
    const float* x      = (const float*)d_in[0];
    const int*   ei     = (const int*)  d_in[1];
    const float* es     = (const float*)d_in[2];
    const float* ewmc   = (const float*)d_in[3];
    const float* pool_w = (const float*)d_in[4];
    const float* pool_b = (const float*)d_in[5];
    const float* lnp_g  = (const float*)d_in[6];
    const float* lnp_b  = (const float*)d_in[7];
    const float* w1     = (const float*)d_in[8];
    const float* b1     = (const float*)d_in[9];
    const float* ln1_g  = (const float*)d_in[10];
    const float* ln1_b  = (const float*)d_in[11];
    const float* w2     = (const float*)d_in[12];
    const float* b2     = (const float*)d_in[13];
    const float* ln2_g  = (const float*)d_in[14];
    const float* ln2_b  = (const float*)d_in[15];
    const float* mu_w   = (const float*)d_in[16];
    const float* mu_b   = (const float*)d_in[17];
    const float* lv_w   = (const float*)d_in[18];
    const float* lv_b   = (const float*)d_in[19];

    const int N = in_sizes[0] / D_DIM;   // 10000
    const int E = in_sizes[2];           // 640000

    // Workspace layout (floats): consts[16] | sy[N] | sy2[N] | syp[N] | y[N*128] | agg[N*128]
    float* ws     = (float*)d_ws;
    float* consts = ws;
    float* sy     = ws + 16;
    float* sy2    = sy + N;
    float* syp    = sy2 + N;
    float* y      = syp + N;
    float* agg    = y + (size_t)N * D_DIM;

    k_setup<<<1, 128, 0, stream>>>(ewmc, pool_b, consts);
    k_pool<<<N / 8, 128, 0, stream>>>(x, pool_w, pool_b, y, sy, sy2, syp);
    hipMemsetAsync(agg, 0, (size_t)N * D_DIM * sizeof(float), stream);
    k_edge<<<4096, 256, 0, stream>>>(ei, es, consts, y, sy, sy2, syp,
                                     pool_b, lnp_g, lnp_b, (int*)agg, E);
    k_mlp<<<N / 8, 256, 0, stream>>>(agg, w1, b1, ln1_g, ln1_b,
                                     w2, b2, ln2_g, ln2_b,
                                     mu_w, mu_b, lv_w, lv_b,
                                     (float*)d_out, N);
}

// Round 2
// 299.458 us; speedup vs baseline: 1.7811x; 1.7811x over previous
//
#include <hip/hip_runtime.h>
#include <math.h>

// Problem constants (shapes fixed by the reference):
// N=10000, E=640000, D=128, H1=256, H2=256, OUT=64
#define D_DIM   128
#define H1_DIM  256
#define H2_DIM  256
#define OUT_DIM 64
#define LN_EPS  1e-5f

// ---------------------------------------------------------------------------
// K0: constants — coef = softplus(ewmc), mpb = mean(pool_b), mpb2 = mean(pool_b^2)
// ---------------------------------------------------------------------------
__global__ void k_setup(const float* __restrict__ ewmc,
                        const float* __restrict__ pb,
                        float* __restrict__ consts) {
    __shared__ float s1[128], s2[128];
    int t = threadIdx.x;
    float v = pb[t];
    s1[t] = v;
    s2[t] = v * v;
    __syncthreads();
    for (int off = 64; off; off >>= 1) {
        if (t < off) { s1[t] += s1[t + off]; s2[t] += s2[t + off]; }
        __syncthreads();
    }
    if (t == 0) {
        float xw = ewmc[0];
        float coef = (xw > 30.f) ? xw : log1pf(expf(xw));
        consts[0] = coef;
        consts[1] = s1[0] * (1.f / 128.f);   // mean(pool_b)
        consts[2] = s2[0] * (1.f / 128.f);   // mean(pool_b^2)
    }
}

// ---------------------------------------------------------------------------
// K1: y = x @ pool_w (no bias) + per-node stats:
//     sy = mean_d(y), sy2 = mean_d(y^2), syp = mean_d(y * pool_b)
// ---------------------------------------------------------------------------
__global__ __launch_bounds__(128) void k_pool(
        const float* __restrict__ x, const float* __restrict__ pw,
        const float* __restrict__ pb,
        float* __restrict__ y, float* __restrict__ sy,
        float* __restrict__ sy2, float* __restrict__ syp) {
    __shared__ float xs[8][129];
    __shared__ float ys[8][129];
    __shared__ float pbs[128];
    int tid = threadIdx.x;
    int row0 = blockIdx.x * 8;
    pbs[tid] = pb[tid];
#pragma unroll
    for (int r = 0; r < 8; ++r) xs[r][tid] = x[(row0 + r) * D_DIM + tid];
    __syncthreads();
    float acc[8];
#pragma unroll
    for (int r = 0; r < 8; ++r) acc[r] = 0.f;
    for (int k = 0; k < D_DIM; ++k) {
        float w = pw[k * D_DIM + tid];
#pragma unroll
        for (int r = 0; r < 8; ++r) acc[r] = fmaf(xs[r][k], w, acc[r]);
    }
#pragma unroll
    for (int r = 0; r < 8; ++r) {
        y[(row0 + r) * D_DIM + tid] = acc[r];
        ys[r][tid] = acc[r];
    }
    __syncthreads();
    if (tid < 24) {
        int r = tid / 3, which = tid % 3;
        float s = 0.f;
        if (which == 0)      for (int k = 0; k < D_DIM; ++k) s += ys[r][k];
        else if (which == 1) for (int k = 0; k < D_DIM; ++k) s += ys[r][k] * ys[r][k];
        else                 for (int k = 0; k < D_DIM; ++k) s += ys[r][k] * pbs[k];
        s *= (1.f / 128.f);
        if (which == 0)      sy [row0 + r] = s;
        else if (which == 1) sy2[row0 + r] = s;
        else                 syp[row0 + r] = s;
    }
}

// ---------------------------------------------------------------------------
// K2a: histogram of dst
// ---------------------------------------------------------------------------
__global__ __launch_bounds__(256) void k_count(
        const int* __restrict__ ei, int* __restrict__ cnt, int E) {
    int stride = gridDim.x * blockDim.x;
    for (int e = blockIdx.x * blockDim.x + threadIdx.x; e < E; e += stride)
        atomicAdd(&cnt[ei[E + e]], 1);
}

// ---------------------------------------------------------------------------
// K2b: single-block exclusive scan over cnt[N] -> offs[N+1], head[N]=offs[N copy]
// ---------------------------------------------------------------------------
__global__ __launch_bounds__(1024) void k_scan(
        const int* __restrict__ cnt, int* __restrict__ offs,
        int* __restrict__ head, int N) {
    __shared__ int part[1024];
    const int t = threadIdx.x;
    const int CH = (N + 1023) / 1024;
    const int base = t * CH;
    int s = 0;
    for (int j = 0; j < CH; ++j) {
        int idx = base + j;
        if (idx < N) s += cnt[idx];
    }
    part[t] = s;
    __syncthreads();
    for (int off = 1; off < 1024; off <<= 1) {
        int v = (t >= off) ? part[t - off] : 0;
        __syncthreads();
        part[t] += v;
        __syncthreads();
    }
    int ex = (t == 0) ? 0 : part[t - 1];
    for (int j = 0; j < CH; ++j) {
        int idx = base + j;
        if (idx < N) {
            offs[idx] = ex;
            head[idx] = ex;
            ex += cnt[idx];
        }
    }
    if (t == 1023) offs[N] = part[1023];
}

// ---------------------------------------------------------------------------
// K2c: scatter edges into CSR order as {src_bits, s} float2 pairs
// ---------------------------------------------------------------------------
__global__ __launch_bounds__(256) void k_scatter(
        const int* __restrict__ ei, const float* __restrict__ es,
        const float* __restrict__ consts,
        int* __restrict__ head, float2* __restrict__ pairs, int E) {
    const float coef = consts[0];
    int stride = gridDim.x * blockDim.x;
    for (int e = blockIdx.x * blockDim.x + threadIdx.x; e < E; e += stride) {
        int src = ei[e];
        int dst = ei[E + e];
        float s = fmaf(coef, es[e], 1.0f);
        int pos = atomicAdd(&head[dst], 1);
        pairs[pos] = make_float2(__int_as_float(src), s);
    }
}

// ---------------------------------------------------------------------------
// K2d: gather-max per dst node. One wave per node; lane owns 2 of 128 dims.
// pooled_d = relu((s*y_d + pb_d - m)*inv*g_d + b_d); max over segment.
// relu hoisted out of the loop (monotone): track max of affine, clamp at end.
// ---------------------------------------------------------------------------
__global__ __launch_bounds__(256) void k_gather(
        const float2* __restrict__ pairs, const int* __restrict__ offs,
        const float* __restrict__ consts,
        const float* __restrict__ y, const float* __restrict__ sy,
        const float* __restrict__ sy2, const float* __restrict__ syp,
        const float* __restrict__ pb, const float* __restrict__ g,
        const float* __restrict__ b, float* __restrict__ agg, int N) {
    const float mpb = consts[1], mpb2 = consts[2];
    const int node = blockIdx.x * 4 + (threadIdx.x >> 6);
    if (node >= N) return;
    const int lane = threadIdx.x & 63;
    const int d0 = lane * 2;
    const float2 pbv = *(const float2*)&pb[d0];
    const float2 gv  = *(const float2*)&g[d0];
    const float2 bv  = *(const float2*)&b[d0];
    float mx0 = -INFINITY, mx1 = -INFINITY;
    const int beg = offs[node], end = offs[node + 1];
    for (int j = beg; j < end; ++j) {
        float2 p = pairs[j];
        int src = __float_as_int(p.x);
        float s = p.y;
        float m   = fmaf(s, sy[src], mpb);
        float et2 = s * s * sy2[src] + 2.f * s * syp[src] + mpb2;
        float inv = rsqrtf(et2 - m * m + LN_EPS);
        float2 yv = *(const float2*)&y[src * D_DIM + d0];
        float t0 = fmaf(s, yv.x, pbv.x);
        float t1 = fmaf(s, yv.y, pbv.y);
        float o0 = fmaf((t0 - m) * inv, gv.x, bv.x);
        float o1 = fmaf((t1 - m) * inv, gv.y, bv.y);
        mx0 = fmaxf(mx0, o0);
        mx1 = fmaxf(mx1, o1);
    }
    int base = node * D_DIM + d0;
    agg[base]     = fmaxf(mx0, 0.f);
    agg[base + 1] = fmaxf(mx1, 0.f);
}

// ---------------------------------------------------------------------------
// K3: fused MLP head. 8 rows per block of 256 threads, all hidden state in LDS.
// ---------------------------------------------------------------------------
__global__ __launch_bounds__(256) void k_mlp(
        const float* __restrict__ agg,
        const float* __restrict__ w1, const float* __restrict__ b1,
        const float* __restrict__ g1, const float* __restrict__ bb1,
        const float* __restrict__ w2, const float* __restrict__ b2,
        const float* __restrict__ g2, const float* __restrict__ bb2,
        const float* __restrict__ muw, const float* __restrict__ mub,
        const float* __restrict__ lvw, const float* __restrict__ lvb,
        float* __restrict__ out, int N) {
    __shared__ float sIn[8][129];
    __shared__ float sH[8][257];
    __shared__ float sH2[8][257];
    __shared__ float sStat[8][2];
    const int tid = threadIdx.x;
    const int row0 = blockIdx.x * 8;

    for (int i = tid; i < 8 * D_DIM; i += 256)
        sIn[i >> 7][i & 127] = agg[row0 * D_DIM + i];
    __syncthreads();

    // ---- layer 1
    float acc[8];
#pragma unroll
    for (int r = 0; r < 8; ++r) acc[r] = 0.f;
    for (int k = 0; k < D_DIM; ++k) {
        float w = w1[k * H1_DIM + tid];
#pragma unroll
        for (int r = 0; r < 8; ++r) acc[r] = fmaf(sIn[r][k], w, acc[r]);
    }
    {
        float bias = b1[tid];
#pragma unroll
        for (int r = 0; r < 8; ++r) { acc[r] += bias; sH[r][tid] = acc[r]; }
    }
    __syncthreads();
    if (tid < 16) {
        int r = tid >> 1, which = tid & 1;
        float s = 0.f;
        if (which == 0) for (int k = 0; k < H1_DIM; ++k) s += sH[r][k];
        else            for (int k = 0; k < H1_DIM; ++k) s += sH[r][k] * sH[r][k];
        sStat[r][which] = s * (1.f / 256.f);
    }
    __syncthreads();
    {
        float gv = g1[tid], bv = bb1[tid];
#pragma unroll
        for (int r = 0; r < 8; ++r) {
            float m = sStat[r][0];
            float v = sStat[r][1] - m * m;
            acc[r] = fmaxf(fmaf((acc[r] - m) * rsqrtf(v + LN_EPS), gv, bv), 0.f);
        }
    }
    __syncthreads();
#pragma unroll
    for (int r = 0; r < 8; ++r) sH[r][tid] = acc[r];
    __syncthreads();

    // ---- layer 2
    float acc2[8];
#pragma unroll
    for (int r = 0; r < 8; ++r) acc2[r] = 0.f;
    for (int k = 0; k < H1_DIM; ++k) {
        float w = w2[k * H2_DIM + tid];
#pragma unroll
        for (int r = 0; r < 8; ++r) acc2[r] = fmaf(sH[r][k], w, acc2[r]);
    }
    {
        float bias = b2[tid];
#pragma unroll
        for (int r = 0; r < 8; ++r) { acc2[r] += bias; sH2[r][tid] = acc2[r]; }
    }
    __syncthreads();
    if (tid < 16) {
        int r = tid >> 1, which = tid & 1;
        float s = 0.f;
        if (which == 0) for (int k = 0; k < H2_DIM; ++k) s += sH2[r][k];
        else            for (int k = 0; k < H2_DIM; ++k) s += sH2[r][k] * sH2[r][k];
        sStat[r][which] = s * (1.f / 256.f);
    }
    __syncthreads();
    {
        float gv = g2[tid], bv = bb2[tid];
#pragma unroll
        for (int r = 0; r < 8; ++r) {
            float m = sStat[r][0];
            float v = sStat[r][1] - m * m;
            acc2[r] = fmaxf(fmaf((acc2[r] - m) * rsqrtf(v + LN_EPS), gv, bv), 0.f);
        }
    }
    __syncthreads();
#pragma unroll
    for (int r = 0; r < 8; ++r) sH2[r][tid] = acc2[r];
    __syncthreads();

    // ---- output heads
    const int col   = tid & 63;
    const int which = (tid >> 6) & 1;   // 0 = mu, 1 = logvar
    const int rh    = tid >> 7;         // row half
    const float* W  = which ? lvw : muw;
    const float ob  = which ? lvb[col] : mub[col];
    float a[4];
#pragma unroll
    for (int rr = 0; rr < 4; ++rr) a[rr] = 0.f;
    for (int k = 0; k < H2_DIM; ++k) {
        float w = W[k * OUT_DIM + col];
#pragma unroll
        for (int rr = 0; rr < 4; ++rr) a[rr] = fmaf(sH2[rh * 4 + rr][k], w, a[rr]);
    }
#pragma unroll
    for (int rr = 0; rr < 4; ++rr) {
        int row = row0 + rh * 4 + rr;
        float val = a[rr] + ob;
        if (which == 0) out[(size_t)row * OUT_DIM + col] = val;
        else            out[(size_t)N * OUT_DIM + (size_t)row * OUT_DIM + col] = expf(0.5f * val);
    }
}

// ---------------------------------------------------------------------------
extern "C" void kernel_launch(void* const* d_in, const int* in_sizes, int n_in,
                              void* d_out, int out_size, void* d_ws, size_t ws_size,
                              hipStream_t stream) {
    const float* x      = (const float*)d_in[0];
    const int*   ei     = (const int*)  d_in[1];
    const float* es     = (const float*)d_in[2];
    const float* ewmc   = (const float*)d_in[3];
    const float* pool_w = (const float*)d_in[4];
    const float* pool_b = (const float*)d_in[5];
    const float* lnp_g  = (const float*)d_in[6];
    const float* lnp_b  = (const float*)d_in[7];
    const float* w1     = (const float*)d_in[8];
    const float* b1     = (const float*)d_in[9];
    const float* ln1_g  = (const float*)d_in[10];
    const float* ln1_b  = (const float*)d_in[11];
    const float* w2     = (const float*)d_in[12];
    const float* b2     = (const float*)d_in[13];
    const float* ln2_g  = (const float*)d_in[14];
    const float* ln2_b  = (const float*)d_in[15];
    const float* mu_w   = (const float*)d_in[16];
    const float* mu_b   = (const float*)d_in[17];
    const float* lv_w   = (const float*)d_in[18];
    const float* lv_b   = (const float*)d_in[19];

    const int N = in_sizes[0] / D_DIM;   // 10000
    const int E = in_sizes[2];           // 640000

    // Workspace layout (4-byte words):
    // consts[16] | sy[N] | sy2[N] | syp[N] | y[N*128] | agg[N*128]
    // | cnt[N] | offs[N+1] | head[N] | (align 16) | pairs[E] (float2)
    float* ws     = (float*)d_ws;
    float* consts = ws;
    float* sy     = ws + 16;
    float* sy2    = sy + N;
    float* syp    = sy2 + N;
    float* y      = syp + N;
    float* agg    = y + (size_t)N * D_DIM;
    size_t w      = 16 + 3 * (size_t)N + 2 * (size_t)N * D_DIM;
    int*   cnt    = (int*)(ws + w); w += N;
    int*   offs   = (int*)(ws + w); w += N + 1;
    int*   head   = (int*)(ws + w); w += N;
    w = (w + 3) & ~(size_t)3;
    float2* pairs = (float2*)(ws + w);

    k_setup<<<1, 128, 0, stream>>>(ewmc, pool_b, consts);
    k_pool<<<N / 8, 128, 0, stream>>>(x, pool_w, pool_b, y, sy, sy2, syp);
    hipMemsetAsync(cnt, 0, (size_t)N * sizeof(int), stream);
    k_count<<<1024, 256, 0, stream>>>(ei, cnt, E);
    k_scan<<<1, 1024, 0, stream>>>(cnt, offs, head, N);
    k_scatter<<<1024, 256, 0, stream>>>(ei, es, consts, head, pairs, E);
    k_gather<<<(N + 3) / 4, 256, 0, stream>>>(pairs, offs, consts, y, sy, sy2, syp,
                                              pool_b, lnp_g, lnp_b, agg, N);
    k_mlp<<<N / 8, 256, 0, stream>>>(agg, w1, b1, ln1_g, ln1_b,
                                     w2, b2, ln2_g, ln2_b,
                                     mu_w, mu_b, lv_w, lv_b,
                                     (float*)d_out, N);
}

// Round 3
// 262.355 us; speedup vs baseline: 2.0330x; 1.1414x over previous
//
#include <hip/hip_runtime.h>
#include <math.h>

// Problem constants (shapes fixed by the reference):
// N=10000, E=640000, D=128, H1=256, H2=256, OUT=64
#define D_DIM   128
#define H1_DIM  256
#define H2_DIM  256
#define OUT_DIM 64
#define LN_EPS  1e-5f

// ---------------------------------------------------------------------------
// K0: constants — coef = softplus(ewmc), mpb = mean(pool_b), mpb2 = mean(pool_b^2)
// ---------------------------------------------------------------------------
__global__ void k_setup(const float* __restrict__ ewmc,
                        const float* __restrict__ pb,
                        float* __restrict__ consts) {
    __shared__ float s1[128], s2[128];
    int t = threadIdx.x;
    float v = pb[t];
    s1[t] = v;
    s2[t] = v * v;
    __syncthreads();
    for (int off = 64; off; off >>= 1) {
        if (t < off) { s1[t] += s1[t + off]; s2[t] += s2[t + off]; }
        __syncthreads();
    }
    if (t == 0) {
        float xw = ewmc[0];
        float coef = (xw > 30.f) ? xw : log1pf(expf(xw));
        consts[0] = coef;
        consts[1] = s1[0] * (1.f / 128.f);   // mean(pool_b)
        consts[2] = s2[0] * (1.f / 128.f);   // mean(pool_b^2)
    }
}

// ---------------------------------------------------------------------------
// K1: y = x @ pool_w + packed per-node stats
//     stat4[n] = { mean(y), mean(y^2), mean(y*pool_b), 0 }
// ---------------------------------------------------------------------------
__global__ __launch_bounds__(128) void k_pool(
        const float* __restrict__ x, const float* __restrict__ pw,
        const float* __restrict__ pb,
        float* __restrict__ y, float4* __restrict__ stat4) {
    __shared__ float xs[8][132];
    __shared__ float ys[8][132];
    __shared__ float pbs[128];
    int tid = threadIdx.x;
    int row0 = blockIdx.x * 8;
    pbs[tid] = pb[tid];
#pragma unroll
    for (int r = 0; r < 8; ++r) xs[r][tid] = x[(row0 + r) * D_DIM + tid];
    __syncthreads();
    float acc[8];
#pragma unroll
    for (int r = 0; r < 8; ++r) acc[r] = 0.f;
    for (int k = 0; k < D_DIM; k += 4) {
        float wa = pw[k * D_DIM + tid];
        float wb = pw[(k + 1) * D_DIM + tid];
        float wc = pw[(k + 2) * D_DIM + tid];
        float wd = pw[(k + 3) * D_DIM + tid];
#pragma unroll
        for (int r = 0; r < 8; ++r) {
            float4 xv = *(const float4*)&xs[r][k];
            acc[r] = fmaf(xv.x, wa, fmaf(xv.y, wb, fmaf(xv.z, wc, fmaf(xv.w, wd, acc[r]))));
        }
    }
#pragma unroll
    for (int r = 0; r < 8; ++r) {
        y[(row0 + r) * D_DIM + tid] = acc[r];
        ys[r][tid] = acc[r];
    }
    __syncthreads();
    if (tid < 24) {
        int r = tid / 3, which = tid % 3;
        float s = 0.f;
        if (which == 0)      for (int k = 0; k < D_DIM; ++k) s += ys[r][k];
        else if (which == 1) for (int k = 0; k < D_DIM; ++k) s += ys[r][k] * ys[r][k];
        else                 for (int k = 0; k < D_DIM; ++k) s += ys[r][k] * pbs[k];
        s *= (1.f / 128.f);
        ((float*)&stat4[row0 + r])[which] = s;
    }
}

// ---------------------------------------------------------------------------
// K2a: histogram of dst
// ---------------------------------------------------------------------------
__global__ __launch_bounds__(256) void k_count(
        const int* __restrict__ ei, int* __restrict__ cnt, int E) {
    int stride = gridDim.x * blockDim.x;
    for (int e = blockIdx.x * blockDim.x + threadIdx.x; e < E; e += stride)
        atomicAdd(&cnt[ei[E + e]], 1);
}

// ---------------------------------------------------------------------------
// K2b: single-block exclusive scan over cnt[N] -> offs[N+1], head[N]
// ---------------------------------------------------------------------------
__global__ __launch_bounds__(1024) void k_scan(
        const int* __restrict__ cnt, int* __restrict__ offs,
        int* __restrict__ head, int N) {
    __shared__ int part[1024];
    const int t = threadIdx.x;
    const int CH = (N + 1023) / 1024;
    const int base = t * CH;
    int s = 0;
    for (int j = 0; j < CH; ++j) {
        int idx = base + j;
        if (idx < N) s += cnt[idx];
    }
    part[t] = s;
    __syncthreads();
    for (int off = 1; off < 1024; off <<= 1) {
        int v = (t >= off) ? part[t - off] : 0;
        __syncthreads();
        part[t] += v;
        __syncthreads();
    }
    int ex = (t == 0) ? 0 : part[t - 1];
    for (int j = 0; j < CH; ++j) {
        int idx = base + j;
        if (idx < N) {
            offs[idx] = ex;
            head[idx] = ex;
            ex += cnt[idx];
        }
    }
    if (t == 1023) offs[N] = part[1023];
}

// ---------------------------------------------------------------------------
// K2c: scatter edges into CSR as float4 {src_bits, s, m, inv}
//      (all per-edge scalar math hoisted here, off gather's critical path)
// ---------------------------------------------------------------------------
__global__ __launch_bounds__(256) void k_scatter(
        const int* __restrict__ ei, const float* __restrict__ es,
        const float* __restrict__ consts, const float4* __restrict__ stat4,
        int* __restrict__ head, float4* __restrict__ pairs, int E) {
    const float coef = consts[0], mpb = consts[1], mpb2 = consts[2];
    int stride = gridDim.x * blockDim.x;
    for (int e = blockIdx.x * blockDim.x + threadIdx.x; e < E; e += stride) {
        int src = ei[e];
        int dst = ei[E + e];
        float s = fmaf(coef, es[e], 1.0f);
        float4 st = stat4[src];
        float m   = fmaf(s, st.x, mpb);
        float et2 = fmaf(s * s, st.y, fmaf(2.f * s, st.z, mpb2));
        float inv = rsqrtf(et2 - m * m + LN_EPS);
        int pos = atomicAdd(&head[dst], 1);
        pairs[pos] = make_float4(__int_as_float(src), s, m, inv);
    }
}

// ---------------------------------------------------------------------------
// K2d: gather-max per dst node, 4-wide unrolled (4 independent y-loads in
// flight per wave). One wave per node; lane owns 2 of 128 dims.
// o_d = (s*y_d + pb_d - m)*inv*g_d + b_d; relu hoisted out via monotonicity.
// ---------------------------------------------------------------------------
__global__ __launch_bounds__(256) void k_gather(
        const float4* __restrict__ pairs, const int* __restrict__ offs,
        const float* __restrict__ y, const float* __restrict__ pb,
        const float* __restrict__ g, const float* __restrict__ b,
        float* __restrict__ agg, int N) {
    const int node = blockIdx.x * 4 + (threadIdx.x >> 6);
    if (node >= N) return;
    const int lane = threadIdx.x & 63;
    const int d0 = lane * 2;
    const float2 pbv = *(const float2*)&pb[d0];
    const float2 gv  = *(const float2*)&g[d0];
    const float2 bv  = *(const float2*)&b[d0];
    float mx0 = -INFINITY, mx1 = -INFINITY;
    int j = offs[node];
    const int end = offs[node + 1];
    for (; j + 4 <= end; j += 4) {
        float4 p0 = pairs[j];
        float4 p1 = pairs[j + 1];
        float4 p2 = pairs[j + 2];
        float4 p3 = pairs[j + 3];
        float2 y0 = *(const float2*)&y[(size_t)__float_as_int(p0.x) * D_DIM + d0];
        float2 y1 = *(const float2*)&y[(size_t)__float_as_int(p1.x) * D_DIM + d0];
        float2 y2 = *(const float2*)&y[(size_t)__float_as_int(p2.x) * D_DIM + d0];
        float2 y3 = *(const float2*)&y[(size_t)__float_as_int(p3.x) * D_DIM + d0];
        mx0 = fmaxf(mx0, fmaf(fmaf(p0.y, y0.x, pbv.x) - p0.z, p0.w * gv.x, bv.x));
        mx1 = fmaxf(mx1, fmaf(fmaf(p0.y, y0.y, pbv.y) - p0.z, p0.w * gv.y, bv.y));
        mx0 = fmaxf(mx0, fmaf(fmaf(p1.y, y1.x, pbv.x) - p1.z, p1.w * gv.x, bv.x));
        mx1 = fmaxf(mx1, fmaf(fmaf(p1.y, y1.y, pbv.y) - p1.z, p1.w * gv.y, bv.y));
        mx0 = fmaxf(mx0, fmaf(fmaf(p2.y, y2.x, pbv.x) - p2.z, p2.w * gv.x, bv.x));
        mx1 = fmaxf(mx1, fmaf(fmaf(p2.y, y2.y, pbv.y) - p2.z, p2.w * gv.y, bv.y));
        mx0 = fmaxf(mx0, fmaf(fmaf(p3.y, y3.x, pbv.x) - p3.z, p3.w * gv.x, bv.x));
        mx1 = fmaxf(mx1, fmaf(fmaf(p3.y, y3.y, pbv.y) - p3.z, p3.w * gv.y, bv.y));
    }
    for (; j < end; ++j) {
        float4 p = pairs[j];
        float2 yv = *(const float2*)&y[(size_t)__float_as_int(p.x) * D_DIM + d0];
        mx0 = fmaxf(mx0, fmaf(fmaf(p.y, yv.x, pbv.x) - p.z, p.w * gv.x, bv.x));
        mx1 = fmaxf(mx1, fmaf(fmaf(p.y, yv.y, pbv.y) - p.z, p.w * gv.y, bv.y));
    }
    int base = node * D_DIM + d0;
    agg[base]     = fmaxf(mx0, 0.f);
    agg[base + 1] = fmaxf(mx1, 0.f);
}

// ---------------------------------------------------------------------------
// K3: fused MLP head. 16 rows per block of 256 threads; float4 LDS reads;
// wave-parallel LN stats via 16-lane shuffle groups.
// ---------------------------------------------------------------------------
__global__ __launch_bounds__(256) void k_mlp(
        const float* __restrict__ agg,
        const float* __restrict__ w1, const float* __restrict__ b1,
        const float* __restrict__ g1, const float* __restrict__ bb1,
        const float* __restrict__ w2, const float* __restrict__ b2,
        const float* __restrict__ g2, const float* __restrict__ bb2,
        const float* __restrict__ muw, const float* __restrict__ mub,
        const float* __restrict__ lvw, const float* __restrict__ lvb,
        float* __restrict__ out, int N) {
    __shared__ float sIn[16][132];   // row stride 132 words = 528 B (16B-aligned)
    __shared__ float sH[16][260];    // 1040 B stride (16B-aligned)
    __shared__ float sH2[16][260];
    __shared__ float sStat[16][2];
    const int tid = threadIdx.x;
    const int row0 = blockIdx.x * 16;

    for (int i = tid; i < 16 * D_DIM; i += 256)
        sIn[i >> 7][i & 127] = agg[row0 * D_DIM + i];
    __syncthreads();

    // ---- layer 1: h1 = agg @ w1 + b1
    float acc[16];
#pragma unroll
    for (int r = 0; r < 16; ++r) acc[r] = 0.f;
    for (int k = 0; k < D_DIM; k += 4) {
        float wa = w1[k * H1_DIM + tid];
        float wb = w1[(k + 1) * H1_DIM + tid];
        float wc = w1[(k + 2) * H1_DIM + tid];
        float wd = w1[(k + 3) * H1_DIM + tid];
#pragma unroll
        for (int r = 0; r < 16; ++r) {
            float4 xv = *(const float4*)&sIn[r][k];
            acc[r] = fmaf(xv.x, wa, fmaf(xv.y, wb, fmaf(xv.z, wc, fmaf(xv.w, wd, acc[r]))));
        }
    }
    {
        float bias = b1[tid];
#pragma unroll
        for (int r = 0; r < 16; ++r) { acc[r] += bias; sH[r][tid] = acc[r]; }
    }
    __syncthreads();
    // stats: 16 threads per row, 16 consecutive elems each, shuffle-reduce
    {
        const int r = tid >> 4, l = tid & 15;
        const float* row = sH[r];
        float s1 = 0.f, s2 = 0.f;
#pragma unroll
        for (int k4 = 0; k4 < 16; k4 += 4) {
            float4 v = *(const float4*)&row[l * 16 + k4];
            s1 += v.x + v.y + v.z + v.w;
            s2 += v.x * v.x + v.y * v.y + v.z * v.z + v.w * v.w;
        }
#pragma unroll
        for (int off = 1; off < 16; off <<= 1) {
            s1 += __shfl_xor(s1, off, 64);
            s2 += __shfl_xor(s2, off, 64);
        }
        if (l == 0) { sStat[r][0] = s1 * (1.f / 256.f); sStat[r][1] = s2 * (1.f / 256.f); }
    }
    __syncthreads();
    {
        float gvv = g1[tid], bvv = bb1[tid];
#pragma unroll
        for (int r = 0; r < 16; ++r) {
            float m = sStat[r][0];
            float v = sStat[r][1] - m * m;
            sH[r][tid] = fmaxf(fmaf((acc[r] - m) * rsqrtf(v + LN_EPS), gvv, bvv), 0.f);
        }
    }
    __syncthreads();

    // ---- layer 2: h2 = h1 @ w2 + b2
    float acc2[16];
#pragma unroll
    for (int r = 0; r < 16; ++r) acc2[r] = 0.f;
    for (int k = 0; k < H1_DIM; k += 4) {
        float wa = w2[k * H2_DIM + tid];
        float wb = w2[(k + 1) * H2_DIM + tid];
        float wc = w2[(k + 2) * H2_DIM + tid];
        float wd = w2[(k + 3) * H2_DIM + tid];
#pragma unroll
        for (int r = 0; r < 16; ++r) {
            float4 xv = *(const float4*)&sH[r][k];
            acc2[r] = fmaf(xv.x, wa, fmaf(xv.y, wb, fmaf(xv.z, wc, fmaf(xv.w, wd, acc2[r]))));
        }
    }
    {
        float bias = b2[tid];
#pragma unroll
        for (int r = 0; r < 16; ++r) { acc2[r] += bias; sH2[r][tid] = acc2[r]; }
    }
    __syncthreads();
    {
        const int r = tid >> 4, l = tid & 15;
        const float* row = sH2[r];
        float s1 = 0.f, s2 = 0.f;
#pragma unroll
        for (int k4 = 0; k4 < 16; k4 += 4) {
            float4 v = *(const float4*)&row[l * 16 + k4];
            s1 += v.x + v.y + v.z + v.w;
            s2 += v.x * v.x + v.y * v.y + v.z * v.z + v.w * v.w;
        }
#pragma unroll
        for (int off = 1; off < 16; off <<= 1) {
            s1 += __shfl_xor(s1, off, 64);
            s2 += __shfl_xor(s2, off, 64);
        }
        if (l == 0) { sStat[r][0] = s1 * (1.f / 256.f); sStat[r][1] = s2 * (1.f / 256.f); }
    }
    __syncthreads();
    {
        float gvv = g2[tid], bvv = bb2[tid];
#pragma unroll
        for (int r = 0; r < 16; ++r) {
            float m = sStat[r][0];
            float v = sStat[r][1] - m * m;
            sH2[r][tid] = fmaxf(fmaf((acc2[r] - m) * rsqrtf(v + LN_EPS), gvv, bvv), 0.f);
        }
    }
    __syncthreads();

    // ---- output heads: tid -> (col, mu/logvar, row-half of 8)
    const int col   = tid & 63;
    const int which = (tid >> 6) & 1;   // 0 = mu, 1 = logvar
    const int rh    = tid >> 7;         // rows rh*8 .. rh*8+7
    const float* W  = which ? lvw : muw;
    const float ob  = which ? lvb[col] : mub[col];
    float a[8];
#pragma unroll
    for (int rr = 0; rr < 8; ++rr) a[rr] = 0.f;
    for (int k = 0; k < H2_DIM; k += 4) {
        float wa = W[k * OUT_DIM + col];
        float wb = W[(k + 1) * OUT_DIM + col];
        float wc = W[(k + 2) * OUT_DIM + col];
        float wd = W[(k + 3) * OUT_DIM + col];
#pragma unroll
        for (int rr = 0; rr < 8; ++rr) {
            float4 h = *(const float4*)&sH2[rh * 8 + rr][k];
            a[rr] = fmaf(h.x, wa, fmaf(h.y, wb, fmaf(h.z, wc, fmaf(h.w, wd, a[rr]))));
        }
    }
#pragma unroll
    for (int rr = 0; rr < 8; ++rr) {
        int row = row0 + rh * 8 + rr;
        float val = a[rr] + ob;
        if (which == 0) out[(size_t)row * OUT_DIM + col] = val;
        else            out[(size_t)N * OUT_DIM + (size_t)row * OUT_DIM + col] = expf(0.5f * val);
    }
}

// ---------------------------------------------------------------------------
extern "C" void kernel_launch(void* const* d_in, const int* in_sizes, int n_in,
                              void* d_out, int out_size, void* d_ws, size_t ws_size,
                              hipStream_t stream) {
    const float* x      = (const float*)d_in[0];
    const int*   ei     = (const int*)  d_in[1];
    const float* es     = (const float*)d_in[2];
    const float* ewmc   = (const float*)d_in[3];
    const float* pool_w = (const float*)d_in[4];
    const float* pool_b = (const float*)d_in[5];
    const float* lnp_g  = (const float*)d_in[6];
    const float* lnp_b  = (const float*)d_in[7];
    const float* w1     = (const float*)d_in[8];
    const float* b1     = (const float*)d_in[9];
    const float* ln1_g  = (const float*)d_in[10];
    const float* ln1_b  = (const float*)d_in[11];
    const float* w2     = (const float*)d_in[12];
    const float* b2     = (const float*)d_in[13];
    const float* ln2_g  = (const float*)d_in[14];
    const float* ln2_b  = (const float*)d_in[15];
    const float* mu_w   = (const float*)d_in[16];
    const float* mu_b   = (const float*)d_in[17];
    const float* lv_w   = (const float*)d_in[18];
    const float* lv_b   = (const float*)d_in[19];

    const int N = in_sizes[0] / D_DIM;   // 10000
    const int E = in_sizes[2];           // 640000

    // Workspace layout (4-byte words):
    // consts[16] | stat4[N] (float4) | y[N*128] | agg[N*128]
    // | cnt[N] | offs[N+1] | head[N] | (align 16B) | pairs[E] (float4)
    float*  ws     = (float*)d_ws;
    float*  consts = ws;
    float4* stat4  = (float4*)(ws + 16);
    float*  y      = ws + 16 + 4 * (size_t)N;
    float*  agg    = y + (size_t)N * D_DIM;
    size_t  w      = 16 + 4 * (size_t)N + 2 * (size_t)N * D_DIM;
    int*    cnt    = (int*)(ws + w); w += N;
    int*    offs   = (int*)(ws + w); w += N + 1;
    int*    head   = (int*)(ws + w); w += N;
    w = (w + 3) & ~(size_t)3;
    float4* pairs  = (float4*)(ws + w);

    k_setup<<<1, 128, 0, stream>>>(ewmc, pool_b, consts);
    k_pool<<<N / 8, 128, 0, stream>>>(x, pool_w, pool_b, y, stat4);
    hipMemsetAsync(cnt, 0, (size_t)N * sizeof(int), stream);
    k_count<<<1024, 256, 0, stream>>>(ei, cnt, E);
    k_scan<<<1, 1024, 0, stream>>>(cnt, offs, head, N);
    k_scatter<<<1024, 256, 0, stream>>>(ei, es, consts, stat4, head, pairs, E);
    k_gather<<<(N + 3) / 4, 256, 0, stream>>>(pairs, offs, y,
                                              pool_b, lnp_g, lnp_b, agg, N);
    k_mlp<<<N / 16, 256, 0, stream>>>(agg, w1, b1, ln1_g, ln1_b,
                                      w2, b2, ln2_g, ln2_b,
                                      mu_w, mu_b, lv_w, lv_b,
                                      (float*)d_out, N);
}

// Round 4
// 242.271 us; speedup vs baseline: 2.2016x; 1.0829x over previous
//
#include <hip/hip_runtime.h>
#include <math.h>

// Problem constants (shapes fixed by the reference):
// N=10000, E=640000, D=128, H1=256, H2=256, OUT=64
#define D_DIM   128
#define H1_DIM  256
#define H2_DIM  256
#define OUT_DIM 64
#define LN_EPS  1e-5f

// ---------------------------------------------------------------------------
// K1: y = x @ pool_w + packed per-node stats
//     stat4[n] = { mean(y), mean(y^2), mean(y*pool_b), 0 }
// Also zeroes cnt[] (8 entries per block) to save a memset dispatch.
// ---------------------------------------------------------------------------
__global__ __launch_bounds__(128) void k_pool(
        const float* __restrict__ x, const float* __restrict__ pw,
        const float* __restrict__ pb,
        float* __restrict__ y, float4* __restrict__ stat4,
        int* __restrict__ cnt) {
    __shared__ float xs[8][132];
    __shared__ float ys[8][132];
    __shared__ float pbs[128];
    int tid = threadIdx.x;
    int row0 = blockIdx.x * 8;
    if (tid < 8) cnt[row0 + tid] = 0;
    pbs[tid] = pb[tid];
#pragma unroll
    for (int r = 0; r < 8; ++r) xs[r][tid] = x[(row0 + r) * D_DIM + tid];
    __syncthreads();
    float acc[8];
#pragma unroll
    for (int r = 0; r < 8; ++r) acc[r] = 0.f;
    for (int k = 0; k < D_DIM; k += 4) {
        float wa = pw[k * D_DIM + tid];
        float wb = pw[(k + 1) * D_DIM + tid];
        float wc = pw[(k + 2) * D_DIM + tid];
        float wd = pw[(k + 3) * D_DIM + tid];
#pragma unroll
        for (int r = 0; r < 8; ++r) {
            float4 xv = *(const float4*)&xs[r][k];
            acc[r] = fmaf(xv.x, wa, fmaf(xv.y, wb, fmaf(xv.z, wc, fmaf(xv.w, wd, acc[r]))));
        }
    }
#pragma unroll
    for (int r = 0; r < 8; ++r) {
        y[(row0 + r) * D_DIM + tid] = acc[r];
        ys[r][tid] = acc[r];
    }
    __syncthreads();
    if (tid < 24) {
        int r = tid / 3, which = tid % 3;
        float s = 0.f;
        if (which == 0)      for (int k = 0; k < D_DIM; ++k) s += ys[r][k];
        else if (which == 1) for (int k = 0; k < D_DIM; ++k) s += ys[r][k] * ys[r][k];
        else                 for (int k = 0; k < D_DIM; ++k) s += ys[r][k] * pbs[k];
        s *= (1.f / 128.f);
        ((float*)&stat4[row0 + r])[which] = s;
    }
}

// ---------------------------------------------------------------------------
// K2a: histogram of dst
// ---------------------------------------------------------------------------
__global__ __launch_bounds__(256) void k_count(
        const int* __restrict__ ei, int* __restrict__ cnt, int E) {
    int stride = gridDim.x * blockDim.x;
    for (int e = blockIdx.x * blockDim.x + threadIdx.x; e < E; e += stride)
        atomicAdd(&cnt[ei[E + e]], 1);
}

// ---------------------------------------------------------------------------
// K2b: single-block exclusive scan over cnt[N] -> offs[N+1], head[N].
// Wave 0 also computes consts (softplus(ewmc), mean(pb), mean(pb^2)) —
// k_setup folded in to save a dispatch.
// ---------------------------------------------------------------------------
__global__ __launch_bounds__(1024) void k_scan(
        const int* __restrict__ cnt, int* __restrict__ offs,
        int* __restrict__ head, float* __restrict__ consts,
        const float* __restrict__ ewmc, const float* __restrict__ pb, int N) {
    const int t = threadIdx.x;
    if (t < 64) {
        float v0 = pb[t], v1 = pb[t + 64];
        float s1 = v0 + v1, s2 = v0 * v0 + v1 * v1;
#pragma unroll
        for (int off = 1; off < 64; off <<= 1) {
            s1 += __shfl_xor(s1, off, 64);
            s2 += __shfl_xor(s2, off, 64);
        }
        if (t == 0) {
            float xw = ewmc[0];
            consts[0] = (xw > 30.f) ? xw : log1pf(expf(xw));
            consts[1] = s1 * (1.f / 128.f);
            consts[2] = s2 * (1.f / 128.f);
        }
    }
    __shared__ int part[1024];
    const int CH = (N + 1023) / 1024;
    const int base = t * CH;
    int s = 0;
    for (int j = 0; j < CH; ++j) {
        int idx = base + j;
        if (idx < N) s += cnt[idx];
    }
    part[t] = s;
    __syncthreads();
    for (int off = 1; off < 1024; off <<= 1) {
        int v = (t >= off) ? part[t - off] : 0;
        __syncthreads();
        part[t] += v;
        __syncthreads();
    }
    int ex = (t == 0) ? 0 : part[t - 1];
    for (int j = 0; j < CH; ++j) {
        int idx = base + j;
        if (idx < N) {
            offs[idx] = ex;
            head[idx] = ex;
            ex += cnt[idx];
        }
    }
    if (t == 1023) offs[N] = part[1023];
}

// ---------------------------------------------------------------------------
// K2c: scatter edges into CSR as float4 {src_bits, s, m, inv}
// ---------------------------------------------------------------------------
__global__ __launch_bounds__(256) void k_scatter(
        const int* __restrict__ ei, const float* __restrict__ es,
        const float* __restrict__ consts, const float4* __restrict__ stat4,
        int* __restrict__ head, float4* __restrict__ pairs, int E) {
    const float coef = consts[0], mpb = consts[1], mpb2 = consts[2];
    int stride = gridDim.x * blockDim.x;
    for (int e = blockIdx.x * blockDim.x + threadIdx.x; e < E; e += stride) {
        int src = ei[e];
        int dst = ei[E + e];
        float s = fmaf(coef, es[e], 1.0f);
        float4 st = stat4[src];
        float m   = fmaf(s, st.x, mpb);
        float et2 = fmaf(s * s, st.y, fmaf(2.f * s, st.z, mpb2));
        float inv = rsqrtf(et2 - m * m + LN_EPS);
        int pos = atomicAdd(&head[dst], 1);
        pairs[pos] = make_float4(__int_as_float(src), s, m, inv);
    }
}

// ---------------------------------------------------------------------------
// K2d: gather-max per dst node, 8-wide unrolled (8 independent y-loads in
// flight per wave). One wave per node; lane owns 2 of 128 dims.
// ---------------------------------------------------------------------------
__global__ __launch_bounds__(256) void k_gather(
        const float4* __restrict__ pairs, const int* __restrict__ offs,
        const float* __restrict__ y, const float* __restrict__ pb,
        const float* __restrict__ g, const float* __restrict__ b,
        float* __restrict__ agg, int N) {
    const int node = blockIdx.x * 4 + (threadIdx.x >> 6);
    if (node >= N) return;
    const int lane = threadIdx.x & 63;
    const int d0 = lane * 2;
    const float2 pbv = *(const float2*)&pb[d0];
    const float2 gv  = *(const float2*)&g[d0];
    const float2 bv  = *(const float2*)&b[d0];
    float mx0 = -INFINITY, mx1 = -INFINITY;
    int j = offs[node];
    const int end = offs[node + 1];
    for (; j + 8 <= end; j += 8) {
        float4 p[8];
        float2 yv[8];
#pragma unroll
        for (int u = 0; u < 8; ++u) p[u] = pairs[j + u];
#pragma unroll
        for (int u = 0; u < 8; ++u)
            yv[u] = *(const float2*)&y[(size_t)__float_as_int(p[u].x) * D_DIM + d0];
#pragma unroll
        for (int u = 0; u < 8; ++u) {
            mx0 = fmaxf(mx0, fmaf(fmaf(p[u].y, yv[u].x, pbv.x) - p[u].z, p[u].w * gv.x, bv.x));
            mx1 = fmaxf(mx1, fmaf(fmaf(p[u].y, yv[u].y, pbv.y) - p[u].z, p[u].w * gv.y, bv.y));
        }
    }
    for (; j < end; ++j) {
        float4 p = pairs[j];
        float2 yv = *(const float2*)&y[(size_t)__float_as_int(p.x) * D_DIM + d0];
        mx0 = fmaxf(mx0, fmaf(fmaf(p.y, yv.x, pbv.x) - p.z, p.w * gv.x, bv.x));
        mx1 = fmaxf(mx1, fmaf(fmaf(p.y, yv.y, pbv.y) - p.z, p.w * gv.y, bv.y));
    }
    int base = node * D_DIM + d0;
    agg[base]     = fmaxf(mx0, 0.f);
    agg[base + 1] = fmaxf(mx1, 0.f);
}

// ---------------------------------------------------------------------------
// K3: fused MLP head. 8 rows per block of 256 threads (21 KB LDS -> 7
// blocks/CU); float4 LDS reads; wave-parallel LN stats (32 lanes/row).
// ---------------------------------------------------------------------------
__global__ __launch_bounds__(256) void k_mlp(
        const float* __restrict__ agg,
        const float* __restrict__ w1, const float* __restrict__ b1,
        const float* __restrict__ g1, const float* __restrict__ bb1,
        const float* __restrict__ w2, const float* __restrict__ b2,
        const float* __restrict__ g2, const float* __restrict__ bb2,
        const float* __restrict__ muw, const float* __restrict__ mub,
        const float* __restrict__ lvw, const float* __restrict__ lvb,
        float* __restrict__ out, int N) {
    __shared__ float sIn[8][132];
    __shared__ float sH[8][260];
    __shared__ float sH2[8][260];
    __shared__ float sStat[8][2];
    const int tid = threadIdx.x;
    const int row0 = blockIdx.x * 8;

    for (int i = tid; i < 8 * D_DIM; i += 256)
        sIn[i >> 7][i & 127] = agg[row0 * D_DIM + i];
    __syncthreads();

    // ---- layer 1: h1 = agg @ w1 + b1
    float acc[8];
#pragma unroll
    for (int r = 0; r < 8; ++r) acc[r] = 0.f;
    for (int k = 0; k < D_DIM; k += 4) {
        float wa = w1[k * H1_DIM + tid];
        float wb = w1[(k + 1) * H1_DIM + tid];
        float wc = w1[(k + 2) * H1_DIM + tid];
        float wd = w1[(k + 3) * H1_DIM + tid];
#pragma unroll
        for (int r = 0; r < 8; ++r) {
            float4 xv = *(const float4*)&sIn[r][k];
            acc[r] = fmaf(xv.x, wa, fmaf(xv.y, wb, fmaf(xv.z, wc, fmaf(xv.w, wd, acc[r]))));
        }
    }
    {
        float bias = b1[tid];
#pragma unroll
        for (int r = 0; r < 8; ++r) { acc[r] += bias; sH[r][tid] = acc[r]; }
    }
    __syncthreads();
    // stats: 32 threads per row, 8 consecutive elems each, shuffle-reduce
    {
        const int r = tid >> 5, l = tid & 31;
        const float* row = sH[r];
        float4 va = *(const float4*)&row[l * 8];
        float4 vb = *(const float4*)&row[l * 8 + 4];
        float s1 = va.x + va.y + va.z + va.w + vb.x + vb.y + vb.z + vb.w;
        float s2 = va.x * va.x + va.y * va.y + va.z * va.z + va.w * va.w
                 + vb.x * vb.x + vb.y * vb.y + vb.z * vb.z + vb.w * vb.w;
#pragma unroll
        for (int off = 1; off < 32; off <<= 1) {
            s1 += __shfl_xor(s1, off, 64);
            s2 += __shfl_xor(s2, off, 64);
        }
        if (l == 0) { sStat[r][0] = s1 * (1.f / 256.f); sStat[r][1] = s2 * (1.f / 256.f); }
    }
    __syncthreads();
    {
        float gvv = g1[tid], bvv = bb1[tid];
#pragma unroll
        for (int r = 0; r < 8; ++r) {
            float m = sStat[r][0];
            float v = sStat[r][1] - m * m;
            sH[r][tid] = fmaxf(fmaf((acc[r] - m) * rsqrtf(v + LN_EPS), gvv, bvv), 0.f);
        }
    }
    __syncthreads();

    // ---- layer 2: h2 = h1 @ w2 + b2
    float acc2[8];
#pragma unroll
    for (int r = 0; r < 8; ++r) acc2[r] = 0.f;
    for (int k = 0; k < H1_DIM; k += 4) {
        float wa = w2[k * H2_DIM + tid];
        float wb = w2[(k + 1) * H2_DIM + tid];
        float wc = w2[(k + 2) * H2_DIM + tid];
        float wd = w2[(k + 3) * H2_DIM + tid];
#pragma unroll
        for (int r = 0; r < 8; ++r) {
            float4 xv = *(const float4*)&sH[r][k];
            acc2[r] = fmaf(xv.x, wa, fmaf(xv.y, wb, fmaf(xv.z, wc, fmaf(xv.w, wd, acc2[r]))));
        }
    }
    {
        float bias = b2[tid];
#pragma unroll
        for (int r = 0; r < 8; ++r) { acc2[r] += bias; sH2[r][tid] = acc2[r]; }
    }
    __syncthreads();
    {
        const int r = tid >> 5, l = tid & 31;
        const float* row = sH2[r];
        float4 va = *(const float4*)&row[l * 8];
        float4 vb = *(const float4*)&row[l * 8 + 4];
        float s1 = va.x + va.y + va.z + va.w + vb.x + vb.y + vb.z + vb.w;
        float s2 = va.x * va.x + va.y * va.y + va.z * va.z + va.w * va.w
                 + vb.x * vb.x + vb.y * vb.y + vb.z * vb.z + vb.w * vb.w;
#pragma unroll
        for (int off = 1; off < 32; off <<= 1) {
            s1 += __shfl_xor(s1, off, 64);
            s2 += __shfl_xor(s2, off, 64);
        }
        if (l == 0) { sStat[r][0] = s1 * (1.f / 256.f); sStat[r][1] = s2 * (1.f / 256.f); }
    }
    __syncthreads();
    {
        float gvv = g2[tid], bvv = bb2[tid];
#pragma unroll
        for (int r = 0; r < 8; ++r) {
            float m = sStat[r][0];
            float v = sStat[r][1] - m * m;
            sH2[r][tid] = fmaxf(fmaf((acc2[r] - m) * rsqrtf(v + LN_EPS), gvv, bvv), 0.f);
        }
    }
    __syncthreads();

    // ---- output heads: tid -> (col, mu/logvar, row-half of 4)
    const int col   = tid & 63;
    const int which = (tid >> 6) & 1;   // 0 = mu, 1 = logvar
    const int rh    = tid >> 7;         // rows rh*4 .. rh*4+3
    const float* W  = which ? lvw : muw;
    const float ob  = which ? lvb[col] : mub[col];
    float a[4];
#pragma unroll
    for (int rr = 0; rr < 4; ++rr) a[rr] = 0.f;
    for (int k = 0; k < H2_DIM; k += 4) {
        float wa = W[k * OUT_DIM + col];
        float wb = W[(k + 1) * OUT_DIM + col];
        float wc = W[(k + 2) * OUT_DIM + col];
        float wd = W[(k + 3) * OUT_DIM + col];
#pragma unroll
        for (int rr = 0; rr < 4; ++rr) {
            float4 h = *(const float4*)&sH2[rh * 4 + rr][k];
            a[rr] = fmaf(h.x, wa, fmaf(h.y, wb, fmaf(h.z, wc, fmaf(h.w, wd, a[rr]))));
        }
    }
#pragma unroll
    for (int rr = 0; rr < 4; ++rr) {
        int row = row0 + rh * 4 + rr;
        float val = a[rr] + ob;
        if (which == 0) out[(size_t)row * OUT_DIM + col] = val;
        else            out[(size_t)N * OUT_DIM + (size_t)row * OUT_DIM + col] = expf(0.5f * val);
    }
}

// ---------------------------------------------------------------------------
extern "C" void kernel_launch(void* const* d_in, const int* in_sizes, int n_in,
                              void* d_out, int out_size, void* d_ws, size_t ws_size,
                              hipStream_t stream) {
    const float* x      = (const float*)d_in[0];
    const int*   ei     = (const int*)  d_in[1];
    const float* es     = (const float*)d_in[2];
    const float* ewmc   = (const float*)d_in[3];
    const float* pool_w = (const float*)d_in[4];
    const float* pool_b = (const float*)d_in[5];
    const float* lnp_g  = (const float*)d_in[6];
    const float* lnp_b  = (const float*)d_in[7];
    const float* w1     = (const float*)d_in[8];
    const float* b1     = (const float*)d_in[9];
    const float* ln1_g  = (const float*)d_in[10];
    const float* ln1_b  = (const float*)d_in[11];
    const float* w2     = (const float*)d_in[12];
    const float* b2     = (const float*)d_in[13];
    const float* ln2_g  = (const float*)d_in[14];
    const float* ln2_b  = (const float*)d_in[15];
    const float* mu_w   = (const float*)d_in[16];
    const float* mu_b   = (const float*)d_in[17];
    const float* lv_w   = (const float*)d_in[18];
    const float* lv_b   = (const float*)d_in[19];

    const int N = in_sizes[0] / D_DIM;   // 10000
    const int E = in_sizes[2];           // 640000

    // Workspace layout (4-byte words):
    // consts[16] | stat4[N] (float4) | y[N*128] | agg[N*128]
    // | cnt[N] | offs[N+1] | head[N] | (align 16B) | pairs[E] (float4)
    float*  ws     = (float*)d_ws;
    float*  consts = ws;
    float4* stat4  = (float4*)(ws + 16);
    float*  y      = ws + 16 + 4 * (size_t)N;
    float*  agg    = y + (size_t)N * D_DIM;
    size_t  w      = 16 + 4 * (size_t)N + 2 * (size_t)N * D_DIM;
    int*    cnt    = (int*)(ws + w); w += N;
    int*    offs   = (int*)(ws + w); w += N + 1;
    int*    head   = (int*)(ws + w); w += N;
    w = (w + 3) & ~(size_t)3;
    float4* pairs  = (float4*)(ws + w);

    k_pool<<<N / 8, 128, 0, stream>>>(x, pool_w, pool_b, y, stat4, cnt);
    k_count<<<1024, 256, 0, stream>>>(ei, cnt, E);
    k_scan<<<1, 1024, 0, stream>>>(cnt, offs, head, consts, ewmc, pool_b, N);
    k_scatter<<<1024, 256, 0, stream>>>(ei, es, consts, stat4, head, pairs, E);
    k_gather<<<(N + 3) / 4, 256, 0, stream>>>(pairs, offs, y,
                                              pool_b, lnp_g, lnp_b, agg, N);
    k_mlp<<<N / 8, 256, 0, stream>>>(agg, w1, b1, ln1_g, ln1_b,
                                     w2, b2, ln2_g, ln2_b,
                                     mu_w, mu_b, lv_w, lv_b,
                                     (float*)d_out, N);
}

// Round 5
// 226.889 us; speedup vs baseline: 2.3508x; 1.0678x over previous
//
#include <hip/hip_runtime.h>
#include <math.h>

// Problem constants (shapes fixed by the reference):
// N=10000, E=640000, D=128, H1=256, H2=256, OUT=64
#define D_DIM   128
#define H1_DIM  256
#define H2_DIM  256
#define OUT_DIM 64
#define LN_EPS  1e-5f

// ---------------------------------------------------------------------------
// K1: y = x @ pool_w + packed per-node stats
//     stat4[n] = { mean(y), mean(y^2), mean(y*pool_b), 0 }
// Also zeroes cnt[] (8 entries per block) to save a memset dispatch.
// ---------------------------------------------------------------------------
__global__ __launch_bounds__(128) void k_pool(
        const float* __restrict__ x, const float* __restrict__ pw,
        const float* __restrict__ pb,
        float* __restrict__ y, float4* __restrict__ stat4,
        int* __restrict__ cnt) {
    __shared__ float xs[8][132];
    __shared__ float ys[8][132];
    __shared__ float pbs[128];
    int tid = threadIdx.x;
    int row0 = blockIdx.x * 8;
    if (tid < 8) cnt[row0 + tid] = 0;
    pbs[tid] = pb[tid];
#pragma unroll
    for (int r = 0; r < 8; ++r) xs[r][tid] = x[(row0 + r) * D_DIM + tid];
    __syncthreads();
    float acc[8];
#pragma unroll
    for (int r = 0; r < 8; ++r) acc[r] = 0.f;
    for (int k = 0; k < D_DIM; k += 4) {
        float wa = pw[k * D_DIM + tid];
        float wb = pw[(k + 1) * D_DIM + tid];
        float wc = pw[(k + 2) * D_DIM + tid];
        float wd = pw[(k + 3) * D_DIM + tid];
#pragma unroll
        for (int r = 0; r < 8; ++r) {
            float4 xv = *(const float4*)&xs[r][k];
            acc[r] = fmaf(xv.x, wa, fmaf(xv.y, wb, fmaf(xv.z, wc, fmaf(xv.w, wd, acc[r]))));
        }
    }
#pragma unroll
    for (int r = 0; r < 8; ++r) {
        y[(row0 + r) * D_DIM + tid] = acc[r];
        ys[r][tid] = acc[r];
    }
    __syncthreads();
    if (tid < 24) {
        int r = tid / 3, which = tid % 3;
        float s = 0.f;
        if (which == 0)      for (int k = 0; k < D_DIM; ++k) s += ys[r][k];
        else if (which == 1) for (int k = 0; k < D_DIM; ++k) s += ys[r][k] * ys[r][k];
        else                 for (int k = 0; k < D_DIM; ++k) s += ys[r][k] * pbs[k];
        s *= (1.f / 128.f);
        ((float*)&stat4[row0 + r])[which] = s;
    }
}

// ---------------------------------------------------------------------------
// K2a: histogram of dst
// ---------------------------------------------------------------------------
__global__ __launch_bounds__(256) void k_count(
        const int* __restrict__ ei, int* __restrict__ cnt, int E) {
    int stride = gridDim.x * blockDim.x;
    for (int e = blockIdx.x * blockDim.x + threadIdx.x; e < E; e += stride)
        atomicAdd(&cnt[ei[E + e]], 1);
}

// ---------------------------------------------------------------------------
// K2b: single-block exclusive scan over cnt[N] -> offs[N+1], head[N].
// Wave 0 also computes consts (softplus(ewmc), mean(pb), mean(pb^2)).
// ---------------------------------------------------------------------------
__global__ __launch_bounds__(1024) void k_scan(
        const int* __restrict__ cnt, int* __restrict__ offs,
        int* __restrict__ head, float* __restrict__ consts,
        const float* __restrict__ ewmc, const float* __restrict__ pb, int N) {
    const int t = threadIdx.x;
    if (t < 64) {
        float v0 = pb[t], v1 = pb[t + 64];
        float s1 = v0 + v1, s2 = v0 * v0 + v1 * v1;
#pragma unroll
        for (int off = 1; off < 64; off <<= 1) {
            s1 += __shfl_xor(s1, off, 64);
            s2 += __shfl_xor(s2, off, 64);
        }
        if (t == 0) {
            float xw = ewmc[0];
            consts[0] = (xw > 30.f) ? xw : log1pf(expf(xw));
            consts[1] = s1 * (1.f / 128.f);
            consts[2] = s2 * (1.f / 128.f);
        }
    }
    __shared__ int part[1024];
    const int CH = (N + 1023) / 1024;
    const int base = t * CH;
    int s = 0;
    for (int j = 0; j < CH; ++j) {
        int idx = base + j;
        if (idx < N) s += cnt[idx];
    }
    part[t] = s;
    __syncthreads();
    for (int off = 1; off < 1024; off <<= 1) {
        int v = (t >= off) ? part[t - off] : 0;
        __syncthreads();
        part[t] += v;
        __syncthreads();
    }
    int ex = (t == 0) ? 0 : part[t - 1];
    for (int j = 0; j < CH; ++j) {
        int idx = base + j;
        if (idx < N) {
            offs[idx] = ex;
            head[idx] = ex;
            ex += cnt[idx];
        }
    }
    if (t == 1023) offs[N] = part[1023];
}

// ---------------------------------------------------------------------------
// K2c: scatter edges into CSR as float4 {src_bits, s, m, inv}
// ---------------------------------------------------------------------------
__global__ __launch_bounds__(256) void k_scatter(
        const int* __restrict__ ei, const float* __restrict__ es,
        const float* __restrict__ consts, const float4* __restrict__ stat4,
        int* __restrict__ head, float4* __restrict__ pairs, int E) {
    const float coef = consts[0], mpb = consts[1], mpb2 = consts[2];
    int stride = gridDim.x * blockDim.x;
    for (int e = blockIdx.x * blockDim.x + threadIdx.x; e < E; e += stride) {
        int src = ei[e];
        int dst = ei[E + e];
        float s = fmaf(coef, es[e], 1.0f);
        float4 st = stat4[src];
        float m   = fmaf(s, st.x, mpb);
        float et2 = fmaf(s * s, st.y, fmaf(2.f * s, st.z, mpb2));
        float inv = rsqrtf(et2 - m * m + LN_EPS);
        int pos = atomicAdd(&head[dst], 1);
        pairs[pos] = make_float4(__int_as_float(src), s, m, inv);
    }
}

// ---------------------------------------------------------------------------
// K2d: gather-max per dst node. One wave per node; 2 edges per wave
// (32 lanes x float4 dims each), unroll 4 -> 8 edges in flight.
// Half-wave partials merged via shfl_xor(32) at the end.
// ---------------------------------------------------------------------------
__global__ __launch_bounds__(256) void k_gather(
        const float4* __restrict__ pairs, const int* __restrict__ offs,
        const float* __restrict__ y, const float* __restrict__ pb,
        const float* __restrict__ g, const float* __restrict__ b,
        float* __restrict__ agg, int N) {
    const int node = blockIdx.x * 4 + (threadIdx.x >> 6);
    if (node >= N) return;
    const int lane = threadIdx.x & 63;
    const int sub  = lane >> 5;          // which edge of the pair this half handles
    const int q    = lane & 31;          // dim quad: dims q*4 .. q*4+3
    const int d0   = q * 4;
    const float4 pbv = *(const float4*)&pb[d0];
    const float4 gv  = *(const float4*)&g[d0];
    const float4 bv  = *(const float4*)&b[d0];
    float4 mx = make_float4(-INFINITY, -INFINITY, -INFINITY, -INFINITY);
    int j = offs[node];
    const int end = offs[node + 1];
    for (; j + 8 <= end; j += 8) {
        float4 p[4], yv[4];
#pragma unroll
        for (int u = 0; u < 4; ++u) p[u] = pairs[j + 2 * u + sub];
#pragma unroll
        for (int u = 0; u < 4; ++u)
            yv[u] = *(const float4*)&y[(size_t)__float_as_int(p[u].x) * D_DIM + d0];
#pragma unroll
        for (int u = 0; u < 4; ++u) {
            float s = p[u].y, m = p[u].z, inv = p[u].w;
            mx.x = fmaxf(mx.x, fmaf(fmaf(s, yv[u].x, pbv.x) - m, inv * gv.x, bv.x));
            mx.y = fmaxf(mx.y, fmaf(fmaf(s, yv[u].y, pbv.y) - m, inv * gv.y, bv.y));
            mx.z = fmaxf(mx.z, fmaf(fmaf(s, yv[u].z, pbv.z) - m, inv * gv.z, bv.z));
            mx.w = fmaxf(mx.w, fmaf(fmaf(s, yv[u].w, pbv.w) - m, inv * gv.w, bv.w));
        }
    }
    for (; j + 2 <= end; j += 2) {
        float4 p = pairs[j + sub];
        float4 yv = *(const float4*)&y[(size_t)__float_as_int(p.x) * D_DIM + d0];
        float s = p.y, m = p.z, inv = p.w;
        mx.x = fmaxf(mx.x, fmaf(fmaf(s, yv.x, pbv.x) - m, inv * gv.x, bv.x));
        mx.y = fmaxf(mx.y, fmaf(fmaf(s, yv.y, pbv.y) - m, inv * gv.y, bv.y));
        mx.z = fmaxf(mx.z, fmaf(fmaf(s, yv.z, pbv.z) - m, inv * gv.z, bv.z));
        mx.w = fmaxf(mx.w, fmaf(fmaf(s, yv.w, pbv.w) - m, inv * gv.w, bv.w));
    }
    if (j < end) {   // last odd edge: both halves compute it (merge dedups)
        float4 p = pairs[j];
        float4 yv = *(const float4*)&y[(size_t)__float_as_int(p.x) * D_DIM + d0];
        float s = p.y, m = p.z, inv = p.w;
        mx.x = fmaxf(mx.x, fmaf(fmaf(s, yv.x, pbv.x) - m, inv * gv.x, bv.x));
        mx.y = fmaxf(mx.y, fmaf(fmaf(s, yv.y, pbv.y) - m, inv * gv.y, bv.y));
        mx.z = fmaxf(mx.z, fmaf(fmaf(s, yv.z, pbv.z) - m, inv * gv.z, bv.z));
        mx.w = fmaxf(mx.w, fmaf(fmaf(s, yv.w, pbv.w) - m, inv * gv.w, bv.w));
    }
    // merge the two half-wave partials
    mx.x = fmaxf(mx.x, __shfl_xor(mx.x, 32, 64));
    mx.y = fmaxf(mx.y, __shfl_xor(mx.y, 32, 64));
    mx.z = fmaxf(mx.z, __shfl_xor(mx.z, 32, 64));
    mx.w = fmaxf(mx.w, __shfl_xor(mx.w, 32, 64));
    if (sub == 0) {
        float4 o;
        o.x = fmaxf(mx.x, 0.f); o.y = fmaxf(mx.y, 0.f);
        o.z = fmaxf(mx.z, 0.f); o.w = fmaxf(mx.w, 0.f);
        *(float4*)&agg[node * D_DIM + d0] = o;
    }
}

// ---------------------------------------------------------------------------
// K3: fused MLP head. 128 threads/block, 8 rows/block, 2 output cols per
// thread (register blocking: each activation float4 feeds 64 FMAs).
// ---------------------------------------------------------------------------
__global__ __launch_bounds__(128) void k_mlp(
        const float* __restrict__ agg,
        const float* __restrict__ w1, const float* __restrict__ b1,
        const float* __restrict__ g1, const float* __restrict__ bb1,
        const float* __restrict__ w2, const float* __restrict__ b2,
        const float* __restrict__ g2, const float* __restrict__ bb2,
        const float* __restrict__ muw, const float* __restrict__ mub,
        const float* __restrict__ lvw, const float* __restrict__ lvb,
        float* __restrict__ out, int N) {
    __shared__ float sIn[8][132];
    __shared__ float sH[8][260];
    __shared__ float sH2[8][260];
    __shared__ float sStat[8][2];
    const int tid = threadIdx.x;       // 0..127
    const int row0 = blockIdx.x * 8;
    const int c0 = tid, c1 = tid + 128;

    for (int i = tid; i < 8 * 32; i += 128) {
        int r = i >> 5, c4 = (i & 31) * 4;
        *(float4*)&sIn[r][c4] = *(const float4*)&agg[(row0 + r) * D_DIM + c4];
    }
    __syncthreads();

    // ---- layer 1: h1 = agg @ w1 + b1 (2 cols/thread)
    float acc0[8], acc1[8];
#pragma unroll
    for (int r = 0; r < 8; ++r) { acc0[r] = 0.f; acc1[r] = 0.f; }
    for (int k = 0; k < D_DIM; k += 4) {
        float wa0 = w1[k * H1_DIM + c0],       wa1 = w1[k * H1_DIM + c1];
        float wb0 = w1[(k + 1) * H1_DIM + c0], wb1 = w1[(k + 1) * H1_DIM + c1];
        float wc0 = w1[(k + 2) * H1_DIM + c0], wc1 = w1[(k + 2) * H1_DIM + c1];
        float wd0 = w1[(k + 3) * H1_DIM + c0], wd1 = w1[(k + 3) * H1_DIM + c1];
#pragma unroll
        for (int r = 0; r < 8; ++r) {
            float4 xv = *(const float4*)&sIn[r][k];
            acc0[r] = fmaf(xv.x, wa0, fmaf(xv.y, wb0, fmaf(xv.z, wc0, fmaf(xv.w, wd0, acc0[r]))));
            acc1[r] = fmaf(xv.x, wa1, fmaf(xv.y, wb1, fmaf(xv.z, wc1, fmaf(xv.w, wd1, acc1[r]))));
        }
    }
    {
        float bias0 = b1[c0], bias1 = b1[c1];
#pragma unroll
        for (int r = 0; r < 8; ++r) {
            acc0[r] += bias0; acc1[r] += bias1;
            sH[r][c0] = acc0[r]; sH[r][c1] = acc1[r];
        }
    }
    __syncthreads();
    // stats: 16 threads per row, 16 consecutive elems each, shuffle-reduce
    {
        const int r = tid >> 4, l = tid & 15;
        const float* row = sH[r];
        float s1 = 0.f, s2 = 0.f;
#pragma unroll
        for (int k4 = 0; k4 < 16; k4 += 4) {
            float4 v = *(const float4*)&row[l * 16 + k4];
            s1 += v.x + v.y + v.z + v.w;
            s2 += v.x * v.x + v.y * v.y + v.z * v.z + v.w * v.w;
        }
#pragma unroll
        for (int off = 1; off < 16; off <<= 1) {
            s1 += __shfl_xor(s1, off, 64);
            s2 += __shfl_xor(s2, off, 64);
        }
        if (l == 0) { sStat[r][0] = s1 * (1.f / 256.f); sStat[r][1] = s2 * (1.f / 256.f); }
    }
    __syncthreads();
    {
        float g0 = g1[c0], g1v = g1[c1], bb0 = bb1[c0], bb1v = bb1[c1];
#pragma unroll
        for (int r = 0; r < 8; ++r) {
            float m = sStat[r][0];
            float inv = rsqrtf(sStat[r][1] - m * m + LN_EPS);
            sH[r][c0] = fmaxf(fmaf((acc0[r] - m) * inv, g0, bb0), 0.f);
            sH[r][c1] = fmaxf(fmaf((acc1[r] - m) * inv, g1v, bb1v), 0.f);
        }
    }
    __syncthreads();

    // ---- layer 2: h2 = h1 @ w2 + b2 (2 cols/thread)
#pragma unroll
    for (int r = 0; r < 8; ++r) { acc0[r] = 0.f; acc1[r] = 0.f; }
    for (int k = 0; k < H1_DIM; k += 4) {
        float wa0 = w2[k * H2_DIM + c0],       wa1 = w2[k * H2_DIM + c1];
        float wb0 = w2[(k + 1) * H2_DIM + c0], wb1 = w2[(k + 1) * H2_DIM + c1];
        float wc0 = w2[(k + 2) * H2_DIM + c0], wc1 = w2[(k + 2) * H2_DIM + c1];
        float wd0 = w2[(k + 3) * H2_DIM + c0], wd1 = w2[(k + 3) * H2_DIM + c1];
#pragma unroll
        for (int r = 0; r < 8; ++r) {
            float4 xv = *(const float4*)&sH[r][k];
            acc0[r] = fmaf(xv.x, wa0, fmaf(xv.y, wb0, fmaf(xv.z, wc0, fmaf(xv.w, wd0, acc0[r]))));
            acc1[r] = fmaf(xv.x, wa1, fmaf(xv.y, wb1, fmaf(xv.z, wc1, fmaf(xv.w, wd1, acc1[r]))));
        }
    }
    {
        float bias0 = b2[c0], bias1 = b2[c1];
#pragma unroll
        for (int r = 0; r < 8; ++r) {
            acc0[r] += bias0; acc1[r] += bias1;
            sH2[r][c0] = acc0[r]; sH2[r][c1] = acc1[r];
        }
    }
    __syncthreads();
    {
        const int r = tid >> 4, l = tid & 15;
        const float* row = sH2[r];
        float s1 = 0.f, s2 = 0.f;
#pragma unroll
        for (int k4 = 0; k4 < 16; k4 += 4) {
            float4 v = *(const float4*)&row[l * 16 + k4];
            s1 += v.x + v.y + v.z + v.w;
            s2 += v.x * v.x + v.y * v.y + v.z * v.z + v.w * v.w;
        }
#pragma unroll
        for (int off = 1; off < 16; off <<= 1) {
            s1 += __shfl_xor(s1, off, 64);
            s2 += __shfl_xor(s2, off, 64);
        }
        if (l == 0) { sStat[r][0] = s1 * (1.f / 256.f); sStat[r][1] = s2 * (1.f / 256.f); }
    }
    __syncthreads();
    {
        float g0 = g2[c0], g1v = g2[c1], bb0 = bb2[c0], bb1v = bb2[c1];
#pragma unroll
        for (int r = 0; r < 8; ++r) {
            float m = sStat[r][0];
            float inv = rsqrtf(sStat[r][1] - m * m + LN_EPS);
            sH2[r][c0] = fmaxf(fmaf((acc0[r] - m) * inv, g0, bb0), 0.f);
            sH2[r][c1] = fmaxf(fmaf((acc1[r] - m) * inv, g1v, bb1v), 0.f);
        }
    }
    __syncthreads();

    // ---- output heads: thread -> (colpair, mu/logvar, row-half)
    const int cp    = tid & 31;          // col pair: cols 2cp, 2cp+1
    const int which = (tid >> 5) & 1;    // 0 = mu, 1 = logvar
    const int rh    = tid >> 6;          // rows rh*4 .. rh*4+3
    const int cc    = 2 * cp;
    const float* W  = which ? lvw : muw;
    const float2 ob = *(const float2*)&(which ? lvb : mub)[cc];
    float a0[4], a1[4];
#pragma unroll
    for (int rr = 0; rr < 4; ++rr) { a0[rr] = 0.f; a1[rr] = 0.f; }
    for (int k = 0; k < H2_DIM; k += 4) {
        float2 wk0 = *(const float2*)&W[k * OUT_DIM + cc];
        float2 wk1 = *(const float2*)&W[(k + 1) * OUT_DIM + cc];
        float2 wk2 = *(const float2*)&W[(k + 2) * OUT_DIM + cc];
        float2 wk3 = *(const float2*)&W[(k + 3) * OUT_DIM + cc];
#pragma unroll
        for (int rr = 0; rr < 4; ++rr) {
            float4 h = *(const float4*)&sH2[rh * 4 + rr][k];
            a0[rr] = fmaf(h.x, wk0.x, fmaf(h.y, wk1.x, fmaf(h.z, wk2.x, fmaf(h.w, wk3.x, a0[rr]))));
            a1[rr] = fmaf(h.x, wk0.y, fmaf(h.y, wk1.y, fmaf(h.z, wk2.y, fmaf(h.w, wk3.y, a1[rr]))));
        }
    }
#pragma unroll
    for (int rr = 0; rr < 4; ++rr) {
        int row = row0 + rh * 4 + rr;
        float v0 = a0[rr] + ob.x;
        float v1 = a1[rr] + ob.y;
        if (which == 0) {
            *(float2*)&out[(size_t)row * OUT_DIM + cc] = make_float2(v0, v1);
        } else {
            float2 sv = make_float2(expf(0.5f * v0), expf(0.5f * v1));
            *(float2*)&out[(size_t)N * OUT_DIM + (size_t)row * OUT_DIM + cc] = sv;
        }
    }
}

// ---------------------------------------------------------------------------
extern "C" void kernel_launch(void* const* d_in, const int* in_sizes, int n_in,
                              void* d_out, int out_size, void* d_ws, size_t ws_size,
                              hipStream_t stream) {
    const float* x      = (const float*)d_in[0];
    const int*   ei     = (const int*)  d_in[1];
    const float* es     = (const float*)d_in[2];
    const float* ewmc   = (const float*)d_in[3];
    const float* pool_w = (const float*)d_in[4];
    const float* pool_b = (const float*)d_in[5];
    const float* lnp_g  = (const float*)d_in[6];
    const float* lnp_b  = (const float*)d_in[7];
    const float* w1     = (const float*)d_in[8];
    const float* b1     = (const float*)d_in[9];
    const float* ln1_g  = (const float*)d_in[10];
    const float* ln1_b  = (const float*)d_in[11];
    const float* w2     = (const float*)d_in[12];
    const float* b2     = (const float*)d_in[13];
    const float* ln2_g  = (const float*)d_in[14];
    const float* ln2_b  = (const float*)d_in[15];
    const float* mu_w   = (const float*)d_in[16];
    const float* mu_b   = (const float*)d_in[17];
    const float* lv_w   = (const float*)d_in[18];
    const float* lv_b   = (const float*)d_in[19];

    const int N = in_sizes[0] / D_DIM;   // 10000
    const int E = in_sizes[2];           // 640000

    // Workspace layout (4-byte words):
    // consts[16] | stat4[N] (float4) | y[N*128] | agg[N*128]
    // | cnt[N] | offs[N+1] | head[N] | (align 16B) | pairs[E] (float4)
    float*  ws     = (float*)d_ws;
    float*  consts = ws;
    float4* stat4  = (float4*)(ws + 16);
    float*  y      = ws + 16 + 4 * (size_t)N;
    float*  agg    = y + (size_t)N * D_DIM;
    size_t  w      = 16 + 4 * (size_t)N + 2 * (size_t)N * D_DIM;
    int*    cnt    = (int*)(ws + w); w += N;
    int*    offs   = (int*)(ws + w); w += N + 1;
    int*    head   = (int*)(ws + w); w += N;
    w = (w + 3) & ~(size_t)3;
    float4* pairs  = (float4*)(ws + w);

    k_pool<<<N / 8, 128, 0, stream>>>(x, pool_w, pool_b, y, stat4, cnt);
    k_count<<<1024, 256, 0, stream>>>(ei, cnt, E);
    k_scan<<<1, 1024, 0, stream>>>(cnt, offs, head, consts, ewmc, pool_b, N);
    k_scatter<<<1024, 256, 0, stream>>>(ei, es, consts, stat4, head, pairs, E);
    k_gather<<<(N + 3) / 4, 256, 0, stream>>>(pairs, offs, y,
                                              pool_b, lnp_g, lnp_b, agg, N);
    k_mlp<<<N / 8, 128, 0, stream>>>(agg, w1, b1, ln1_g, ln1_b,
                                     w2, b2, ln2_g, ln2_b,
                                     mu_w, mu_b, lv_w, lv_b,
                                     (float*)d_out, N);
}

// Round 6
// 222.206 us; speedup vs baseline: 2.4004x; 1.0211x over previous
//
#include <hip/hip_runtime.h>
#include <math.h>

// Problem constants (shapes fixed by the reference):
// N=10000, E=640000, D=128, H1=256, H2=256, OUT=64
#define D_DIM   128
#define H1_DIM  256
#define H2_DIM  256
#define OUT_DIM 64
#define LN_EPS  1e-5f

// ---------------------------------------------------------------------------
// K1: y = x @ pool_w + packed per-node stats
//     stat4[n] = { mean(y), mean(y^2), mean(y*pool_b), 0 }
// Fused: dst-histogram for this block's edge slice (atomics overlap compute).
// ---------------------------------------------------------------------------
__global__ __launch_bounds__(128) void k_pool(
        const float* __restrict__ x, const float* __restrict__ pw,
        const float* __restrict__ pb,
        float* __restrict__ y, float4* __restrict__ stat4,
        const int* __restrict__ ei, int* __restrict__ cnt, int E, int epb) {
    __shared__ float xs[8][132];
    __shared__ float ys[8][132];
    __shared__ float pbs[128];
    int tid = threadIdx.x;
    int row0 = blockIdx.x * 8;
    pbs[tid] = pb[tid];
#pragma unroll
    for (int r = 0; r < 8; ++r) xs[r][tid] = x[(row0 + r) * D_DIM + tid];
    // edge-count slice: fire-and-forget atomics, overlap with FMA loop below
    {
        int ebeg = blockIdx.x * epb;
        int eend = ebeg + epb; if (eend > E) eend = E;
        for (int e = ebeg + tid; e < eend; e += 128)
            atomicAdd(&cnt[ei[E + e]], 1);
    }
    __syncthreads();
    float acc[8];
#pragma unroll
    for (int r = 0; r < 8; ++r) acc[r] = 0.f;
    for (int k = 0; k < D_DIM; k += 4) {
        float wa = pw[k * D_DIM + tid];
        float wb = pw[(k + 1) * D_DIM + tid];
        float wc = pw[(k + 2) * D_DIM + tid];
        float wd = pw[(k + 3) * D_DIM + tid];
#pragma unroll
        for (int r = 0; r < 8; ++r) {
            float4 xv = *(const float4*)&xs[r][k];
            acc[r] = fmaf(xv.x, wa, fmaf(xv.y, wb, fmaf(xv.z, wc, fmaf(xv.w, wd, acc[r]))));
        }
    }
#pragma unroll
    for (int r = 0; r < 8; ++r) {
        y[(row0 + r) * D_DIM + tid] = acc[r];
        ys[r][tid] = acc[r];
    }
    __syncthreads();
    if (tid < 24) {
        int r = tid / 3, which = tid % 3;
        float s = 0.f;
        if (which == 0)      for (int k = 0; k < D_DIM; ++k) s += ys[r][k];
        else if (which == 1) for (int k = 0; k < D_DIM; ++k) s += ys[r][k] * ys[r][k];
        else                 for (int k = 0; k < D_DIM; ++k) s += ys[r][k] * pbs[k];
        s *= (1.f / 128.f);
        ((float*)&stat4[row0 + r])[which] = s;
    }
}

// ---------------------------------------------------------------------------
// K2b: single-block exclusive scan over cnt[N] -> offs[N+1], head[N].
// Wave 0 also computes consts (softplus(ewmc), mean(pb), mean(pb^2)).
// ---------------------------------------------------------------------------
__global__ __launch_bounds__(1024) void k_scan(
        const int* __restrict__ cnt, int* __restrict__ offs,
        int* __restrict__ head, float* __restrict__ consts,
        const float* __restrict__ ewmc, const float* __restrict__ pb, int N) {
    const int t = threadIdx.x;
    if (t < 64) {
        float v0 = pb[t], v1 = pb[t + 64];
        float s1 = v0 + v1, s2 = v0 * v0 + v1 * v1;
#pragma unroll
        for (int off = 1; off < 64; off <<= 1) {
            s1 += __shfl_xor(s1, off, 64);
            s2 += __shfl_xor(s2, off, 64);
        }
        if (t == 0) {
            float xw = ewmc[0];
            consts[0] = (xw > 30.f) ? xw : log1pf(expf(xw));
            consts[1] = s1 * (1.f / 128.f);
            consts[2] = s2 * (1.f / 128.f);
        }
    }
    __shared__ int part[1024];
    const int CH = (N + 1023) / 1024;
    const int base = t * CH;
    int s = 0;
    for (int j = 0; j < CH; ++j) {
        int idx = base + j;
        if (idx < N) s += cnt[idx];
    }
    part[t] = s;
    __syncthreads();
    for (int off = 1; off < 1024; off <<= 1) {
        int v = (t >= off) ? part[t - off] : 0;
        __syncthreads();
        part[t] += v;
        __syncthreads();
    }
    int ex = (t == 0) ? 0 : part[t - 1];
    for (int j = 0; j < CH; ++j) {
        int idx = base + j;
        if (idx < N) {
            offs[idx] = ex;
            head[idx] = ex;
            ex += cnt[idx];
        }
    }
    if (t == 1023) offs[N] = part[1023];
}

// ---------------------------------------------------------------------------
// K2c: scatter edges into CSR as float4 {src_bits, s, m, inv}
// ---------------------------------------------------------------------------
__global__ __launch_bounds__(256) void k_scatter(
        const int* __restrict__ ei, const float* __restrict__ es,
        const float* __restrict__ consts, const float4* __restrict__ stat4,
        int* __restrict__ head, float4* __restrict__ pairs, int E) {
    const float coef = consts[0], mpb = consts[1], mpb2 = consts[2];
    int stride = gridDim.x * blockDim.x;
    for (int e = blockIdx.x * blockDim.x + threadIdx.x; e < E; e += stride) {
        int src = ei[e];
        int dst = ei[E + e];
        float s = fmaf(coef, es[e], 1.0f);
        float4 st = stat4[src];
        float m   = fmaf(s, st.x, mpb);
        float et2 = fmaf(s * s, st.y, fmaf(2.f * s, st.z, mpb2));
        float inv = rsqrtf(et2 - m * m + LN_EPS);
        int pos = atomicAdd(&head[dst], 1);
        pairs[pos] = make_float4(__int_as_float(src), s, m, inv);
    }
}

// ---------------------------------------------------------------------------
// K2d: gather-max per dst node. One wave per node; 2 edges per wave
// (32 lanes x float4 dims each), unroll 6 -> 12 edges in flight.
// Half-wave partials merged via shfl_xor(32) at the end.
// ---------------------------------------------------------------------------
__global__ __launch_bounds__(256) void k_gather(
        const float4* __restrict__ pairs, const int* __restrict__ offs,
        const float* __restrict__ y, const float* __restrict__ pb,
        const float* __restrict__ g, const float* __restrict__ b,
        float* __restrict__ agg, int N) {
    const int node = blockIdx.x * 4 + (threadIdx.x >> 6);
    if (node >= N) return;
    const int lane = threadIdx.x & 63;
    const int sub  = lane >> 5;          // which edge of the pair this half handles
    const int q    = lane & 31;          // dim quad: dims q*4 .. q*4+3
    const int d0   = q * 4;
    const float4 pbv = *(const float4*)&pb[d0];
    const float4 gv  = *(const float4*)&g[d0];
    const float4 bv  = *(const float4*)&b[d0];
    float4 mx = make_float4(-INFINITY, -INFINITY, -INFINITY, -INFINITY);
    int j = offs[node];
    const int end = offs[node + 1];
    for (; j + 12 <= end; j += 12) {
        float4 p[6], yv[6];
#pragma unroll
        for (int u = 0; u < 6; ++u) p[u] = pairs[j + 2 * u + sub];
#pragma unroll
        for (int u = 0; u < 6; ++u)
            yv[u] = *(const float4*)&y[(size_t)__float_as_int(p[u].x) * D_DIM + d0];
#pragma unroll
        for (int u = 0; u < 6; ++u) {
            float s = p[u].y, m = p[u].z, inv = p[u].w;
            mx.x = fmaxf(mx.x, fmaf(fmaf(s, yv[u].x, pbv.x) - m, inv * gv.x, bv.x));
            mx.y = fmaxf(mx.y, fmaf(fmaf(s, yv[u].y, pbv.y) - m, inv * gv.y, bv.y));
            mx.z = fmaxf(mx.z, fmaf(fmaf(s, yv[u].z, pbv.z) - m, inv * gv.z, bv.z));
            mx.w = fmaxf(mx.w, fmaf(fmaf(s, yv[u].w, pbv.w) - m, inv * gv.w, bv.w));
        }
    }
    for (; j + 2 <= end; j += 2) {
        float4 p = pairs[j + sub];
        float4 yv = *(const float4*)&y[(size_t)__float_as_int(p.x) * D_DIM + d0];
        float s = p.y, m = p.z, inv = p.w;
        mx.x = fmaxf(mx.x, fmaf(fmaf(s, yv.x, pbv.x) - m, inv * gv.x, bv.x));
        mx.y = fmaxf(mx.y, fmaf(fmaf(s, yv.y, pbv.y) - m, inv * gv.y, bv.y));
        mx.z = fmaxf(mx.z, fmaf(fmaf(s, yv.z, pbv.z) - m, inv * gv.z, bv.z));
        mx.w = fmaxf(mx.w, fmaf(fmaf(s, yv.w, pbv.w) - m, inv * gv.w, bv.w));
    }
    if (j < end) {   // last odd edge: both halves compute it (merge dedups)
        float4 p = pairs[j];
        float4 yv = *(const float4*)&y[(size_t)__float_as_int(p.x) * D_DIM + d0];
        float s = p.y, m = p.z, inv = p.w;
        mx.x = fmaxf(mx.x, fmaf(fmaf(s, yv.x, pbv.x) - m, inv * gv.x, bv.x));
        mx.y = fmaxf(mx.y, fmaf(fmaf(s, yv.y, pbv.y) - m, inv * gv.y, bv.y));
        mx.z = fmaxf(mx.z, fmaf(fmaf(s, yv.z, pbv.z) - m, inv * gv.z, bv.z));
        mx.w = fmaxf(mx.w, fmaf(fmaf(s, yv.w, pbv.w) - m, inv * gv.w, bv.w));
    }
    // merge the two half-wave partials
    mx.x = fmaxf(mx.x, __shfl_xor(mx.x, 32, 64));
    mx.y = fmaxf(mx.y, __shfl_xor(mx.y, 32, 64));
    mx.z = fmaxf(mx.z, __shfl_xor(mx.z, 32, 64));
    mx.w = fmaxf(mx.w, __shfl_xor(mx.w, 32, 64));
    if (sub == 0) {
        float4 o;
        o.x = fmaxf(mx.x, 0.f); o.y = fmaxf(mx.y, 0.f);
        o.z = fmaxf(mx.z, 0.f); o.w = fmaxf(mx.w, 0.f);
        *(float4*)&agg[node * D_DIM + d0] = o;
    }
}

// ---------------------------------------------------------------------------
// K3: fused MLP head. 256 threads, 8 rows/block; rows split by half-block
// (threads t and t+128 read identical weight addresses -> L1 dedup, L2
// traffic unchanged); 2 cols/thread, 4 rows/thread -> 8 accs. 4 waves/block
// at 1250 blocks = 2x R5 latency hiding at the same weight traffic.
// ---------------------------------------------------------------------------
__global__ __launch_bounds__(256) void k_mlp(
        const float* __restrict__ agg,
        const float* __restrict__ w1, const float* __restrict__ b1,
        const float* __restrict__ g1, const float* __restrict__ bb1,
        const float* __restrict__ w2, const float* __restrict__ b2,
        const float* __restrict__ g2, const float* __restrict__ bb2,
        const float* __restrict__ muw, const float* __restrict__ mub,
        const float* __restrict__ lvw, const float* __restrict__ lvb,
        float* __restrict__ out, int N) {
    __shared__ float sIn[8][132];
    __shared__ float sH[8][260];
    __shared__ float sH2[8][260];
    __shared__ float sStat[8][2];
    const int tid = threadIdx.x;       // 0..255
    const int row0 = blockIdx.x * 8;
    const int half = tid >> 7;         // 0: rows 0-3, 1: rows 4-7
    const int ht   = tid & 127;
    const int c0 = ht, c1 = ht + 128;
    const int rbase = half * 4;

    {   // stage agg rows: 256 threads x 1 float4 = 8 rows x 32 quads
        int r = tid >> 5, q = (tid & 31) * 4;
        *(float4*)&sIn[r][q] = *(const float4*)&agg[(size_t)(row0 + r) * D_DIM + q];
    }
    __syncthreads();

    // ---- layer 1: h1 = agg @ w1 + b1 (2 cols x 4 rows per thread)
    float acc0[4], acc1[4];
#pragma unroll
    for (int r = 0; r < 4; ++r) { acc0[r] = 0.f; acc1[r] = 0.f; }
    for (int k = 0; k < D_DIM; k += 4) {
        float wa0 = w1[k * H1_DIM + c0],       wa1 = w1[k * H1_DIM + c1];
        float wb0 = w1[(k + 1) * H1_DIM + c0], wb1 = w1[(k + 1) * H1_DIM + c1];
        float wc0 = w1[(k + 2) * H1_DIM + c0], wc1 = w1[(k + 2) * H1_DIM + c1];
        float wd0 = w1[(k + 3) * H1_DIM + c0], wd1 = w1[(k + 3) * H1_DIM + c1];
#pragma unroll
        for (int r = 0; r < 4; ++r) {
            float4 xv = *(const float4*)&sIn[rbase + r][k];
            acc0[r] = fmaf(xv.x, wa0, fmaf(xv.y, wb0, fmaf(xv.z, wc0, fmaf(xv.w, wd0, acc0[r]))));
            acc1[r] = fmaf(xv.x, wa1, fmaf(xv.y, wb1, fmaf(xv.z, wc1, fmaf(xv.w, wd1, acc1[r]))));
        }
    }
    {
        float bias0 = b1[c0], bias1 = b1[c1];
#pragma unroll
        for (int r = 0; r < 4; ++r) {
            acc0[r] += bias0; acc1[r] += bias1;
            sH[rbase + r][c0] = acc0[r]; sH[rbase + r][c1] = acc1[r];
        }
    }
    __syncthreads();
    // stats: 32 threads per row, 8 consecutive elems each, shuffle-reduce
    {
        const int r = tid >> 5, l = tid & 31;
        const float* row = sH[r];
        float4 va = *(const float4*)&row[l * 8];
        float4 vb = *(const float4*)&row[l * 8 + 4];
        float s1 = va.x + va.y + va.z + va.w + vb.x + vb.y + vb.z + vb.w;
        float s2 = va.x * va.x + va.y * va.y + va.z * va.z + va.w * va.w
                 + vb.x * vb.x + vb.y * vb.y + vb.z * vb.z + vb.w * vb.w;
#pragma unroll
        for (int off = 1; off < 32; off <<= 1) {
            s1 += __shfl_xor(s1, off, 64);
            s2 += __shfl_xor(s2, off, 64);
        }
        if (l == 0) { sStat[r][0] = s1 * (1.f / 256.f); sStat[r][1] = s2 * (1.f / 256.f); }
    }
    __syncthreads();
    {
        float g0 = g1[c0], g1v = g1[c1], bb0 = bb1[c0], bb1v = bb1[c1];
#pragma unroll
        for (int r = 0; r < 4; ++r) {
            float m = sStat[rbase + r][0];
            float inv = rsqrtf(sStat[rbase + r][1] - m * m + LN_EPS);
            sH[rbase + r][c0] = fmaxf(fmaf((acc0[r] - m) * inv, g0, bb0), 0.f);
            sH[rbase + r][c1] = fmaxf(fmaf((acc1[r] - m) * inv, g1v, bb1v), 0.f);
        }
    }
    __syncthreads();

    // ---- layer 2: h2 = h1 @ w2 + b2
#pragma unroll
    for (int r = 0; r < 4; ++r) { acc0[r] = 0.f; acc1[r] = 0.f; }
    for (int k = 0; k < H1_DIM; k += 4) {
        float wa0 = w2[k * H2_DIM + c0],       wa1 = w2[k * H2_DIM + c1];
        float wb0 = w2[(k + 1) * H2_DIM + c0], wb1 = w2[(k + 1) * H2_DIM + c1];
        float wc0 = w2[(k + 2) * H2_DIM + c0], wc1 = w2[(k + 2) * H2_DIM + c1];
        float wd0 = w2[(k + 3) * H2_DIM + c0], wd1 = w2[(k + 3) * H2_DIM + c1];
#pragma unroll
        for (int r = 0; r < 4; ++r) {
            float4 xv = *(const float4*)&sH[rbase + r][k];
            acc0[r] = fmaf(xv.x, wa0, fmaf(xv.y, wb0, fmaf(xv.z, wc0, fmaf(xv.w, wd0, acc0[r]))));
            acc1[r] = fmaf(xv.x, wa1, fmaf(xv.y, wb1, fmaf(xv.z, wc1, fmaf(xv.w, wd1, acc1[r]))));
        }
    }
    {
        float bias0 = b2[c0], bias1 = b2[c1];
#pragma unroll
        for (int r = 0; r < 4; ++r) {
            acc0[r] += bias0; acc1[r] += bias1;
            sH2[rbase + r][c0] = acc0[r]; sH2[rbase + r][c1] = acc1[r];
        }
    }
    __syncthreads();
    {
        const int r = tid >> 5, l = tid & 31;
        const float* row = sH2[r];
        float4 va = *(const float4*)&row[l * 8];
        float4 vb = *(const float4*)&row[l * 8 + 4];
        float s1 = va.x + va.y + va.z + va.w + vb.x + vb.y + vb.z + vb.w;
        float s2 = va.x * va.x + va.y * va.y + va.z * va.z + va.w * va.w
                 + vb.x * vb.x + vb.y * vb.y + vb.z * vb.z + vb.w * vb.w;
#pragma unroll
        for (int off = 1; off < 32; off <<= 1) {
            s1 += __shfl_xor(s1, off, 64);
            s2 += __shfl_xor(s2, off, 64);
        }
        if (l == 0) { sStat[r][0] = s1 * (1.f / 256.f); sStat[r][1] = s2 * (1.f / 256.f); }
    }
    __syncthreads();
    {
        float g0 = g2[c0], g1v = g2[c1], bb0 = bb2[c0], bb1v = bb2[c1];
#pragma unroll
        for (int r = 0; r < 4; ++r) {
            float m = sStat[rbase + r][0];
            float inv = rsqrtf(sStat[rbase + r][1] - m * m + LN_EPS);
            sH2[rbase + r][c0] = fmaxf(fmaf((acc0[r] - m) * inv, g0, bb0), 0.f);
            sH2[rbase + r][c1] = fmaxf(fmaf((acc1[r] - m) * inv, g1v, bb1v), 0.f);
        }
    }
    __syncthreads();

    // ---- output heads: thread -> (col, mu/logvar, row-half of 4)
    const int col   = tid & 63;
    const int which = (tid >> 6) & 1;    // 0 = mu, 1 = logvar
    const int rh    = tid >> 7;          // rows rh*4 .. rh*4+3
    const float* W  = which ? lvw : muw;
    const float ob  = which ? lvb[col] : mub[col];
    float a[4];
#pragma unroll
    for (int rr = 0; rr < 4; ++rr) a[rr] = 0.f;
    for (int k = 0; k < H2_DIM; k += 4) {
        float wa = W[k * OUT_DIM + col];
        float wb = W[(k + 1) * OUT_DIM + col];
        float wc = W[(k + 2) * OUT_DIM + col];
        float wd = W[(k + 3) * OUT_DIM + col];
#pragma unroll
        for (int rr = 0; rr < 4; ++rr) {
            float4 h = *(const float4*)&sH2[rh * 4 + rr][k];
            a[rr] = fmaf(h.x, wa, fmaf(h.y, wb, fmaf(h.z, wc, fmaf(h.w, wd, a[rr]))));
        }
    }
#pragma unroll
    for (int rr = 0; rr < 4; ++rr) {
        int row = row0 + rh * 4 + rr;
        float val = a[rr] + ob;
        if (which == 0) out[(size_t)row * OUT_DIM + col] = val;
        else            out[(size_t)N * OUT_DIM + (size_t)row * OUT_DIM + col] = expf(0.5f * val);
    }
}

// ---------------------------------------------------------------------------
extern "C" void kernel_launch(void* const* d_in, const int* in_sizes, int n_in,
                              void* d_out, int out_size, void* d_ws, size_t ws_size,
                              hipStream_t stream) {
    const float* x      = (const float*)d_in[0];
    const int*   ei     = (const int*)  d_in[1];
    const float* es     = (const float*)d_in[2];
    const float* ewmc   = (const float*)d_in[3];
    const float* pool_w = (const float*)d_in[4];
    const float* pool_b = (const float*)d_in[5];
    const float* lnp_g  = (const float*)d_in[6];
    const float* lnp_b  = (const float*)d_in[7];
    const float* w1     = (const float*)d_in[8];
    const float* b1     = (const float*)d_in[9];
    const float* ln1_g  = (const float*)d_in[10];
    const float* ln1_b  = (const float*)d_in[11];
    const float* w2     = (const float*)d_in[12];
    const float* b2     = (const float*)d_in[13];
    const float* ln2_g  = (const float*)d_in[14];
    const float* ln2_b  = (const float*)d_in[15];
    const float* mu_w   = (const float*)d_in[16];
    const float* mu_b   = (const float*)d_in[17];
    const float* lv_w   = (const float*)d_in[18];
    const float* lv_b   = (const float*)d_in[19];

    const int N = in_sizes[0] / D_DIM;   // 10000
    const int E = in_sizes[2];           // 640000

    // Workspace layout (4-byte words):
    // consts[16] | stat4[N] (float4) | y[N*128] | agg[N*128]
    // | cnt[N] | offs[N+1] | head[N] | (align 16B) | pairs[E] (float4)
    float*  ws     = (float*)d_ws;
    float*  consts = ws;
    float4* stat4  = (float4*)(ws + 16);
    float*  y      = ws + 16 + 4 * (size_t)N;
    float*  agg    = y + (size_t)N * D_DIM;
    size_t  w      = 16 + 4 * (size_t)N + 2 * (size_t)N * D_DIM;
    int*    cnt    = (int*)(ws + w); w += N;
    int*    offs   = (int*)(ws + w); w += N + 1;
    int*    head   = (int*)(ws + w); w += N;
    w = (w + 3) & ~(size_t)3;
    float4* pairs  = (float4*)(ws + w);

    const int nb  = N / 8;                    // 1250 blocks
    const int epb = (E + nb - 1) / nb;        // 512 edges per block

    hipMemsetAsync(cnt, 0, (size_t)N * sizeof(int), stream);
    k_pool<<<nb, 128, 0, stream>>>(x, pool_w, pool_b, y, stat4, ei, cnt, E, epb);
    k_scan<<<1, 1024, 0, stream>>>(cnt, offs, head, consts, ewmc, pool_b, N);
    k_scatter<<<1024, 256, 0, stream>>>(ei, es, consts, stat4, head, pairs, E);
    k_gather<<<(N + 3) / 4, 256, 0, stream>>>(pairs, offs, y,
                                              pool_b, lnp_g, lnp_b, agg, N);
    k_mlp<<<nb, 256, 0, stream>>>(agg, w1, b1, ln1_g, ln1_b,
                                  w2, b2, ln2_g, ln2_b,
                                  mu_w, mu_b, lv_w, lv_b,
                                  (float*)d_out, N);
}

// Round 8
// 179.536 us; speedup vs baseline: 2.9708x; 1.2377x over previous
//
#include <hip/hip_runtime.h>
#include <math.h>

// Problem constants (shapes fixed by the reference):
// N=10000, E=640000, D=128, H1=256, H2=256, OUT=64
#define D_DIM   128
#define H1_DIM  256
#define H2_DIM  256
#define OUT_DIM 64
#define LN_EPS  1e-5f

typedef __attribute__((ext_vector_type(8))) short bf16x8;   // 8 bf16 (4 VGPRs)
typedef __attribute__((ext_vector_type(4))) float f32x4;    // MFMA acc

__device__ __forceinline__ unsigned short bf16rne(float v) {
    unsigned int b = __float_as_uint(v);
    return (unsigned short)((b + 0x7FFFu + ((b >> 16) & 1u)) >> 16);
}

// ---------------------------------------------------------------------------
// K1: y = x @ pool_w + packed per-node stats
//     stat4[n] = { mean(y), mean(y^2), mean(y*pool_b), 0 }
// Fused extras: dst-histogram slice; blocks 0-127 also pack the MLP weights
// into bf16 MFMA B-fragment order (wp1/wp2/wpH) — overlapped, off the
// critical path (k_mlp runs last).
// ---------------------------------------------------------------------------
__global__ __launch_bounds__(128) void k_pool(
        const float* __restrict__ x, const float* __restrict__ pw,
        const float* __restrict__ pb,
        float* __restrict__ y, float4* __restrict__ stat4,
        const int* __restrict__ ei, int* __restrict__ cnt, int E, int epb,
        const float* __restrict__ w1, const float* __restrict__ w2,
        const float* __restrict__ muw, const float* __restrict__ lvw,
        short* __restrict__ wp1, short* __restrict__ wp2,
        short* __restrict__ wpH) {
    __shared__ float xs[8][132];
    __shared__ float ys[8][132];
    __shared__ float pbs[128];
    int tid = threadIdx.x;
    int row0 = blockIdx.x * 8;
    pbs[tid] = pb[tid];
#pragma unroll
    for (int r = 0; r < 8; ++r) xs[r][tid] = x[(row0 + r) * D_DIM + tid];
    // edge-count slice (fire-and-forget atomics overlap the FMA loop)
    {
        int ebeg = blockIdx.x * epb;
        int eend = ebeg + epb; if (eend > E) eend = E;
        for (int e = ebeg + tid; e < eend; e += 128)
            atomicAdd(&cnt[ei[E + e]], 1);
    }
    __syncthreads();
    float acc[8];
#pragma unroll
    for (int r = 0; r < 8; ++r) acc[r] = 0.f;
    for (int k = 0; k < D_DIM; k += 4) {
        float wa = pw[k * D_DIM + tid];
        float wb = pw[(k + 1) * D_DIM + tid];
        float wc = pw[(k + 2) * D_DIM + tid];
        float wd = pw[(k + 3) * D_DIM + tid];
#pragma unroll
        for (int r = 0; r < 8; ++r) {
            float4 xv = *(const float4*)&xs[r][k];
            acc[r] = fmaf(xv.x, wa, fmaf(xv.y, wb, fmaf(xv.z, wc, fmaf(xv.w, wd, acc[r]))));
        }
    }
#pragma unroll
    for (int r = 0; r < 8; ++r) {
        y[(row0 + r) * D_DIM + tid] = acc[r];
        ys[r][tid] = acc[r];
    }
    __syncthreads();
    if (tid < 24) {
        int r = tid / 3, which = tid % 3;
        float s = 0.f;
        if (which == 0)      for (int k = 0; k < D_DIM; ++k) s += ys[r][k];
        else if (which == 1) for (int k = 0; k < D_DIM; ++k) s += ys[r][k] * ys[r][k];
        else                 for (int k = 0; k < D_DIM; ++k) s += ys[r][k] * pbs[k];
        s *= (1.f / 128.f);
        ((float*)&stat4[row0 + r])[which] = s;
    }
    // ---- weight packing tail: 128 blocks x 128 threads = 16384 fragment-lanes
    // layout: frag f = (ct*KT + kt)*64 + lane;  lane l: col = ctBase + (l&15),
    // k = kt*32 + 8*(l>>4) + j (j=0..7 contiguous bf16 in the 16B entry).
    if (blockIdx.x < 128) {
        int i = blockIdx.x * 128 + tid;      // 0..16383
        const float* W; int Ndim, kt, ln, col; short* dst;
        if (i < 4096) {                      // w1: K=128 (KT=4), N=256 (16 ct)
            int q = i >> 6; ln = i & 63; kt = q & 3; int ct = q >> 2;
            W = w1; Ndim = H1_DIM; col = ct * 16 + (ln & 15); dst = wp1 + i * 8;
        } else if (i < 12288) {              // w2: K=256 (KT=8), N=256
            int i2 = i - 4096; int q = i2 >> 6; ln = i2 & 63; kt = q & 7; int ct = q >> 3;
            W = w2; Ndim = H2_DIM; col = ct * 16 + (ln & 15); dst = wp2 + i2 * 8;
        } else {                             // heads: K=256 (KT=8), ct 0-3 mu, 4-7 lv
            int i3 = i - 12288; int q = i3 >> 6; ln = i3 & 63; kt = q & 7; int ct = q >> 3;
            Ndim = OUT_DIM; dst = wpH + i3 * 8;
            if (ct < 4) { W = muw; col = ct * 16 + (ln & 15); }
            else        { W = lvw; col = (ct - 4) * 16 + (ln & 15); }
        }
        int k0 = kt * 32 + (ln >> 4) * 8;
        unsigned int u[4];
#pragma unroll
        for (int jj = 0; jj < 4; ++jj) {
            float a = W[(k0 + 2 * jj) * Ndim + col];
            float b = W[(k0 + 2 * jj + 1) * Ndim + col];
            u[jj] = (unsigned int)bf16rne(a) | ((unsigned int)bf16rne(b) << 16);
        }
        *(uint4*)dst = make_uint4(u[0], u[1], u[2], u[3]);
    }
}

// ---------------------------------------------------------------------------
// K2b: single-block exclusive scan over cnt[N] -> offs[N+1], head[N].
// Wave 0 also computes consts (softplus(ewmc), mean(pb), mean(pb^2)).
// ---------------------------------------------------------------------------
__global__ __launch_bounds__(1024) void k_scan(
        const int* __restrict__ cnt, int* __restrict__ offs,
        int* __restrict__ head, float* __restrict__ consts,
        const float* __restrict__ ewmc, const float* __restrict__ pb, int N) {
    const int t = threadIdx.x;
    if (t < 64) {
        float v0 = pb[t], v1 = pb[t + 64];
        float s1 = v0 + v1, s2 = v0 * v0 + v1 * v1;
#pragma unroll
        for (int off = 1; off < 64; off <<= 1) {
            s1 += __shfl_xor(s1, off, 64);
            s2 += __shfl_xor(s2, off, 64);
        }
        if (t == 0) {
            float xw = ewmc[0];
            consts[0] = (xw > 30.f) ? xw : log1pf(expf(xw));
            consts[1] = s1 * (1.f / 128.f);
            consts[2] = s2 * (1.f / 128.f);
        }
    }
    __shared__ int part[1024];
    const int CH = (N + 1023) / 1024;
    const int base = t * CH;
    int s = 0;
    for (int j = 0; j < CH; ++j) {
        int idx = base + j;
        if (idx < N) s += cnt[idx];
    }
    part[t] = s;
    __syncthreads();
    for (int off = 1; off < 1024; off <<= 1) {
        int v = (t >= off) ? part[t - off] : 0;
        __syncthreads();
        part[t] += v;
        __syncthreads();
    }
    int ex = (t == 0) ? 0 : part[t - 1];
    for (int j = 0; j < CH; ++j) {
        int idx = base + j;
        if (idx < N) {
            offs[idx] = ex;
            head[idx] = ex;
            ex += cnt[idx];
        }
    }
    if (t == 1023) offs[N] = part[1023];
}

// ---------------------------------------------------------------------------
// K2c: scatter edges into CSR as float4 {src_bits, s, m, inv}
// ---------------------------------------------------------------------------
__global__ __launch_bounds__(256) void k_scatter(
        const int* __restrict__ ei, const float* __restrict__ es,
        const float* __restrict__ consts, const float4* __restrict__ stat4,
        int* __restrict__ head, float4* __restrict__ pairs, int E) {
    const float coef = consts[0], mpb = consts[1], mpb2 = consts[2];
    int stride = gridDim.x * blockDim.x;
    for (int e = blockIdx.x * blockDim.x + threadIdx.x; e < E; e += stride) {
        int src = ei[e];
        int dst = ei[E + e];
        float s = fmaf(coef, es[e], 1.0f);
        float4 st = stat4[src];
        float m   = fmaf(s, st.x, mpb);
        float et2 = fmaf(s * s, st.y, fmaf(2.f * s, st.z, mpb2));
        float inv = rsqrtf(et2 - m * m + LN_EPS);
        int pos = atomicAdd(&head[dst], 1);
        pairs[pos] = make_float4(__int_as_float(src), s, m, inv);
    }
}

// ---------------------------------------------------------------------------
// K2d: gather-max per dst node. One wave per node; 2 edges per wave
// (32 lanes x float4 dims each), unroll 6 -> 12 edges in flight.
// ---------------------------------------------------------------------------
__global__ __launch_bounds__(256) void k_gather(
        const float4* __restrict__ pairs, const int* __restrict__ offs,
        const float* __restrict__ y, const float* __restrict__ pb,
        const float* __restrict__ g, const float* __restrict__ b,
        float* __restrict__ agg, int N) {
    const int node = blockIdx.x * 4 + (threadIdx.x >> 6);
    if (node >= N) return;
    const int lane = threadIdx.x & 63;
    const int sub  = lane >> 5;
    const int q    = lane & 31;
    const int d0   = q * 4;
    const float4 pbv = *(const float4*)&pb[d0];
    const float4 gv  = *(const float4*)&g[d0];
    const float4 bv  = *(const float4*)&b[d0];
    float4 mx = make_float4(-INFINITY, -INFINITY, -INFINITY, -INFINITY);
    int j = offs[node];
    const int end = offs[node + 1];
    for (; j + 12 <= end; j += 12) {
        float4 p[6], yv[6];
#pragma unroll
        for (int u = 0; u < 6; ++u) p[u] = pairs[j + 2 * u + sub];
#pragma unroll
        for (int u = 0; u < 6; ++u)
            yv[u] = *(const float4*)&y[(size_t)__float_as_int(p[u].x) * D_DIM + d0];
#pragma unroll
        for (int u = 0; u < 6; ++u) {
            float s = p[u].y, m = p[u].z, inv = p[u].w;
            mx.x = fmaxf(mx.x, fmaf(fmaf(s, yv[u].x, pbv.x) - m, inv * gv.x, bv.x));
            mx.y = fmaxf(mx.y, fmaf(fmaf(s, yv[u].y, pbv.y) - m, inv * gv.y, bv.y));
            mx.z = fmaxf(mx.z, fmaf(fmaf(s, yv[u].z, pbv.z) - m, inv * gv.z, bv.z));
            mx.w = fmaxf(mx.w, fmaf(fmaf(s, yv[u].w, pbv.w) - m, inv * gv.w, bv.w));
        }
    }
    for (; j + 2 <= end; j += 2) {
        float4 p = pairs[j + sub];
        float4 yv = *(const float4*)&y[(size_t)__float_as_int(p.x) * D_DIM + d0];
        float s = p.y, m = p.z, inv = p.w;
        mx.x = fmaxf(mx.x, fmaf(fmaf(s, yv.x, pbv.x) - m, inv * gv.x, bv.x));
        mx.y = fmaxf(mx.y, fmaf(fmaf(s, yv.y, pbv.y) - m, inv * gv.y, bv.y));
        mx.z = fmaxf(mx.z, fmaf(fmaf(s, yv.z, pbv.z) - m, inv * gv.z, bv.z));
        mx.w = fmaxf(mx.w, fmaf(fmaf(s, yv.w, pbv.w) - m, inv * gv.w, bv.w));
    }
    if (j < end) {
        float4 p = pairs[j];
        float4 yv = *(const float4*)&y[(size_t)__float_as_int(p.x) * D_DIM + d0];
        float s = p.y, m = p.z, inv = p.w;
        mx.x = fmaxf(mx.x, fmaf(fmaf(s, yv.x, pbv.x) - m, inv * gv.x, bv.x));
        mx.y = fmaxf(mx.y, fmaf(fmaf(s, yv.y, pbv.y) - m, inv * gv.y, bv.y));
        mx.z = fmaxf(mx.z, fmaf(fmaf(s, yv.z, pbv.z) - m, inv * gv.z, bv.z));
        mx.w = fmaxf(mx.w, fmaf(fmaf(s, yv.w, pbv.w) - m, inv * gv.w, bv.w));
    }
    mx.x = fmaxf(mx.x, __shfl_xor(mx.x, 32, 64));
    mx.y = fmaxf(mx.y, __shfl_xor(mx.y, 32, 64));
    mx.z = fmaxf(mx.z, __shfl_xor(mx.z, 32, 64));
    mx.w = fmaxf(mx.w, __shfl_xor(mx.w, 32, 64));
    if (sub == 0) {
        float4 o;
        o.x = fmaxf(mx.x, 0.f); o.y = fmaxf(mx.y, 0.f);
        o.z = fmaxf(mx.z, 0.f); o.w = fmaxf(mx.w, 0.f);
        *(float4*)&agg[node * D_DIM + d0] = o;
    }
}

// ---------------------------------------------------------------------------
// K3: MFMA MLP. 512 threads (8 waves), 16 rows/block, 625 blocks.
// A-frags (activations) live in LDS as bf16 in fragment order:
//   aPack[kt][lane][j]: lane l -> row = l&15, k = kt*32 + 8*(l>>4) + j.
// B-frags (weights) pre-packed by k_pool (wp1/wp2/wpH), coalesced 16B/lane.
// A and B share the same k-convention, so the true HW k-permutation cancels.
// D-frag: col = lane&15, row = 4*(lane>>4) + reg   (m89-verified layout).
// ---------------------------------------------------------------------------
__global__ __launch_bounds__(512) void k_mlp(
        const float* __restrict__ agg,
        const short* __restrict__ wp1, const short* __restrict__ wp2,
        const short* __restrict__ wpH,
        const float* __restrict__ b1, const float* __restrict__ g1,
        const float* __restrict__ bb1,
        const float* __restrict__ b2, const float* __restrict__ g2,
        const float* __restrict__ bb2,
        const float* __restrict__ mub, const float* __restrict__ lvb,
        float* __restrict__ out, int N) {
    __shared__ __align__(16) short aPack[8 * 64 * 8];   // 8 KB: K up to 256
    __shared__ float sPart[16][8][2];
    __shared__ float sM[16], sI[16];
    const int tid  = threadIdx.x;
    const int w    = tid >> 6;
    const int lane = tid & 63;
    const int gq   = lane >> 4;        // quarter-wave group 0..3
    const int c16  = lane & 15;
    const int row0 = blockIdx.x * 16;

    // ---- stage agg (16x128 f32) -> bf16 A-frags, kt 0..3
    {
        int r  = tid >> 5;             // 0..15
        int k0 = (tid & 31) * 4;       // 0..124
        float4 v = *(const float4*)&agg[(size_t)(row0 + r) * D_DIM + k0];
        int kt = k0 >> 5, sub = (k0 >> 3) & 3, j = k0 & 7;
        int lp = r | (sub << 4);
        unsigned int u0 = (unsigned int)bf16rne(v.x) | ((unsigned int)bf16rne(v.y) << 16);
        unsigned int u1 = (unsigned int)bf16rne(v.z) | ((unsigned int)bf16rne(v.w) << 16);
        *(uint2*)&aPack[kt * 512 + lp * 8 + j] = make_uint2(u0, u1);
    }
    __syncthreads();

    const int ct0 = 2 * w, ct1 = 2 * w + 1;
    f32x4 A0 = {0.f, 0.f, 0.f, 0.f}, A1 = {0.f, 0.f, 0.f, 0.f};

    // ---- layer 1: K=128 (kt 0..3), 16 col-tiles over 8 waves (2 each)
#pragma unroll
    for (int kt = 0; kt < 4; ++kt) {
        bf16x8 av = *(bf16x8*)&aPack[(kt * 64 + lane) * 8];
        bf16x8 bv0 = *(const bf16x8*)&wp1[((ct0 * 4 + kt) * 64 + lane) * 8];
        bf16x8 bv1 = *(const bf16x8*)&wp1[((ct1 * 4 + kt) * 64 + lane) * 8];
        A0 = __builtin_amdgcn_mfma_f32_16x16x32_bf16(av, bv0, A0, 0, 0, 0);
        A1 = __builtin_amdgcn_mfma_f32_16x16x32_bf16(av, bv1, A1, 0, 0, 0);
    }
    {
        int col0 = ct0 * 16 + c16, col1 = ct1 * 16 + c16;
        float bias0 = b1[col0], bias1 = b1[col1];
        float v0[4], v1[4];
#pragma unroll
        for (int r = 0; r < 4; ++r) {
            v0[r] = A0[r] + bias0; v1[r] = A1[r] + bias1;
            float s1 = v0[r] + v1[r];
            float s2 = v0[r] * v0[r] + v1[r] * v1[r];
#pragma unroll
            for (int m = 1; m < 16; m <<= 1) {
                s1 += __shfl_xor(s1, m, 64);
                s2 += __shfl_xor(s2, m, 64);
            }
            if (c16 == 0) { sPart[gq * 4 + r][w][0] = s1; sPart[gq * 4 + r][w][1] = s2; }
        }
        __syncthreads();
        if (tid < 16) {
            float t1 = 0.f, t2 = 0.f;
#pragma unroll
            for (int ww = 0; ww < 8; ++ww) { t1 += sPart[tid][ww][0]; t2 += sPart[tid][ww][1]; }
            float m = t1 * (1.f / 256.f);
            sM[tid] = m;
            sI[tid] = rsqrtf(t2 * (1.f / 256.f) - m * m + LN_EPS);
        }
        __syncthreads();
        float gc0 = g1[col0], bc0 = bb1[col0];
        float gc1 = g1[col1], bc1 = bb1[col1];
#pragma unroll
        for (int r = 0; r < 4; ++r) {
            int row = gq * 4 + r;
            float m = sM[row], inv = sI[row];
            float h0 = fmaxf(fmaf((v0[r] - m) * inv, gc0, bc0), 0.f);
            float h1 = fmaxf(fmaf((v1[r] - m) * inv, gc1, bc1), 0.f);
            aPack[(col0 >> 5) * 512 + (row | (((col0 >> 3) & 3) << 4)) * 8 + (col0 & 7)] = (short)bf16rne(h0);
            aPack[(col1 >> 5) * 512 + (row | (((col1 >> 3) & 3) << 4)) * 8 + (col1 & 7)] = (short)bf16rne(h1);
        }
    }
    __syncthreads();

    // ---- layer 2: K=256 (kt 0..7)
    A0 = (f32x4){0.f, 0.f, 0.f, 0.f}; A1 = (f32x4){0.f, 0.f, 0.f, 0.f};
#pragma unroll
    for (int kt = 0; kt < 8; ++kt) {
        bf16x8 av = *(bf16x8*)&aPack[(kt * 64 + lane) * 8];
        bf16x8 bv0 = *(const bf16x8*)&wp2[((ct0 * 8 + kt) * 64 + lane) * 8];
        bf16x8 bv1 = *(const bf16x8*)&wp2[((ct1 * 8 + kt) * 64 + lane) * 8];
        A0 = __builtin_amdgcn_mfma_f32_16x16x32_bf16(av, bv0, A0, 0, 0, 0);
        A1 = __builtin_amdgcn_mfma_f32_16x16x32_bf16(av, bv1, A1, 0, 0, 0);
    }
    {
        int col0 = ct0 * 16 + c16, col1 = ct1 * 16 + c16;
        float bias0 = b2[col0], bias1 = b2[col1];
        float v0[4], v1[4];
#pragma unroll
        for (int r = 0; r < 4; ++r) {
            v0[r] = A0[r] + bias0; v1[r] = A1[r] + bias1;
            float s1 = v0[r] + v1[r];
            float s2 = v0[r] * v0[r] + v1[r] * v1[r];
#pragma unroll
            for (int m = 1; m < 16; m <<= 1) {
                s1 += __shfl_xor(s1, m, 64);
                s2 += __shfl_xor(s2, m, 64);
            }
            if (c16 == 0) { sPart[gq * 4 + r][w][0] = s1; sPart[gq * 4 + r][w][1] = s2; }
        }
        __syncthreads();
        if (tid < 16) {
            float t1 = 0.f, t2 = 0.f;
#pragma unroll
            for (int ww = 0; ww < 8; ++ww) { t1 += sPart[tid][ww][0]; t2 += sPart[tid][ww][1]; }
            float m = t1 * (1.f / 256.f);
            sM[tid] = m;
            sI[tid] = rsqrtf(t2 * (1.f / 256.f) - m * m + LN_EPS);
        }
        __syncthreads();
        float gc0 = g2[col0], bc0 = bb2[col0];
        float gc1 = g2[col1], bc1 = bb2[col1];
#pragma unroll
        for (int r = 0; r < 4; ++r) {
            int row = gq * 4 + r;
            float m = sM[row], inv = sI[row];
            float h0 = fmaxf(fmaf((v0[r] - m) * inv, gc0, bc0), 0.f);
            float h1 = fmaxf(fmaf((v1[r] - m) * inv, gc1, bc1), 0.f);
            aPack[(col0 >> 5) * 512 + (row | (((col0 >> 3) & 3) << 4)) * 8 + (col0 & 7)] = (short)bf16rne(h0);
            aPack[(col1 >> 5) * 512 + (row | (((col1 >> 3) & 3) << 4)) * 8 + (col1 & 7)] = (short)bf16rne(h1);
        }
    }
    __syncthreads();

    // ---- heads: 8 col-tiles (ct 0-3 mu, 4-7 logvar), wave w -> ct w; K=256
    {
        f32x4 H = {0.f, 0.f, 0.f, 0.f};
#pragma unroll
        for (int kt = 0; kt < 8; ++kt) {
            bf16x8 av = *(bf16x8*)&aPack[(kt * 64 + lane) * 8];
            bf16x8 bv = *(const bf16x8*)&wpH[((w * 8 + kt) * 64 + lane) * 8];
            H = __builtin_amdgcn_mfma_f32_16x16x32_bf16(av, bv, H, 0, 0, 0);
        }
        int colh = (w & 3) * 16 + c16;
        if (w < 4) {
            float bias = mub[colh];
#pragma unroll
            for (int r = 0; r < 4; ++r)
                out[(size_t)(row0 + gq * 4 + r) * OUT_DIM + colh] = H[r] + bias;
        } else {
            float bias = lvb[colh];
#pragma unroll
            for (int r = 0; r < 4; ++r)
                out[(size_t)N * OUT_DIM + (size_t)(row0 + gq * 4 + r) * OUT_DIM + colh] =
                    expf(0.5f * (H[r] + bias));
        }
    }
}

// ---------------------------------------------------------------------------
extern "C" void kernel_launch(void* const* d_in, const int* in_sizes, int n_in,
                              void* d_out, int out_size, void* d_ws, size_t ws_size,
                              hipStream_t stream) {
    const float* x      = (const float*)d_in[0];
    const int*   ei     = (const int*)  d_in[1];
    const float* es     = (const float*)d_in[2];
    const float* ewmc   = (const float*)d_in[3];
    const float* pool_w = (const float*)d_in[4];
    const float* pool_b = (const float*)d_in[5];
    const float* lnp_g  = (const float*)d_in[6];
    const float* lnp_b  = (const float*)d_in[7];
    const float* w1     = (const float*)d_in[8];
    const float* b1     = (const float*)d_in[9];
    const float* ln1_g  = (const float*)d_in[10];
    const float* ln1_b  = (const float*)d_in[11];
    const float* w2     = (const float*)d_in[12];
    const float* b2     = (const float*)d_in[13];
    const float* ln2_g  = (const float*)d_in[14];
    const float* ln2_b  = (const float*)d_in[15];
    const float* mu_w   = (const float*)d_in[16];
    const float* mu_b   = (const float*)d_in[17];
    const float* lv_w   = (const float*)d_in[18];
    const float* lv_b   = (const float*)d_in[19];

    const int N = in_sizes[0] / D_DIM;   // 10000
    const int E = in_sizes[2];           // 640000

    // Workspace layout (4-byte words):
    // consts[16] | stat4[N] | y[N*128] | agg[N*128] | cnt[N] | offs[N+1] |
    // head[N] | (align) | wp1 (16384 w) | wp2 (32768 w) | wpH (16384 w) |
    // pairs[E] (float4)
    float*  ws     = (float*)d_ws;
    float*  consts = ws;
    float4* stat4  = (float4*)(ws + 16);
    float*  y      = ws + 16 + 4 * (size_t)N;
    float*  agg    = y + (size_t)N * D_DIM;
    size_t  w      = 16 + 4 * (size_t)N + 2 * (size_t)N * D_DIM;
    int*    cnt    = (int*)(ws + w); w += N;
    int*    offs   = (int*)(ws + w); w += N + 1;
    int*    head   = (int*)(ws + w); w += N;
    w = (w + 3) & ~(size_t)3;
    short*  wp1    = (short*)(ws + w); w += 16384;   // 32768 shorts = 16384 words
    short*  wp2    = (short*)(ws + w); w += 32768;   // 65536 shorts = 32768 words
    short*  wpH    = (short*)(ws + w); w += 16384;   // 32768 shorts = 16384 words
    float4* pairs  = (float4*)(ws + w);

    const int nb  = N / 8;                    // 1250 blocks
    const int epb = (E + nb - 1) / nb;        // 512 edges per block

    hipMemsetAsync(cnt, 0, (size_t)N * sizeof(int), stream);
    k_pool<<<nb, 128, 0, stream>>>(x, pool_w, pool_b, y, stat4, ei, cnt, E, epb,
                                   w1, w2, mu_w, lv_w, wp1, wp2, wpH);
    k_scan<<<1, 1024, 0, stream>>>(cnt, offs, head, consts, ewmc, pool_b, N);
    k_scatter<<<1024, 256, 0, stream>>>(ei, es, consts, stat4, head, pairs, E);
    k_gather<<<(N + 3) / 4, 256, 0, stream>>>(pairs, offs, y,
                                              pool_b, lnp_g, lnp_b, agg, N);
    k_mlp<<<N / 16, 512, 0, stream>>>(agg, wp1, wp2, wpH,
                                      b1, ln1_g, ln1_b,
                                      b2, ln2_g, ln2_b,
                                      mu_b, lv_b, (float*)d_out, N);
}